// Round 6
// baseline (1845.210 us; speedup 1.0000x reference)
//
#include <hip/hip_runtime.h>
#include <math.h>

#define V_    10000
#define E_    150
#define F_    200
#define TL_   7
#define B_    2048
#define NSEG_ 3
#define EPS_  1e-5f
#define SLOPE_ 0.01f
#define NB64  (B_/64)
#define NVB   157          // ceil(10000/64) v-parts for MFMA Y-GEMM
#define KQ_   7            // K chunks of 32 for F_=200 (padded 224)

typedef unsigned short u16;
typedef __attribute__((ext_vector_type(8))) short bf16x8;
typedef __attribute__((ext_vector_type(4))) float f32x4;

__device__ __forceinline__ float leaky_f(float x){ return x >= 0.f ? x : SLOPE_*x; }
__device__ __forceinline__ u16 bf16_rne(float x){
  unsigned u = __float_as_uint(x);
  unsigned r = (u + 0x7FFFu + ((u>>16)&1u)) >> 16;
  return (u16)r;
}
__device__ __forceinline__ float bf16_to_f(u16 h){ return __uint_as_float(((unsigned)h)<<16); }

// ---------------------------------------------------------------- transpose
__global__ void transpose_k(const float* __restrict__ in, float* __restrict__ out,
                            int R, int C)
{
  __shared__ float tile[32][33];
  const long long bofs = (long long)blockIdx.z * R * C;
  in += bofs; out += bofs;
  const int c0 = blockIdx.x*32, r0 = blockIdx.y*32;
  const int tx = threadIdx.x, ty = threadIdx.y;  // (32,8)
  for (int i = ty; i < 32; i += 8) {
    int r = r0 + i, c = c0 + tx;
    if (r < R && c < C) tile[i][tx] = in[(long long)r*C + c];
  }
  __syncthreads();
  for (int i = ty; i < 32; i += 8) {
    int c = c0 + i, r = r0 + tx;
    if (c < C && r < R) out[(long long)c*R + r] = tile[tx][i];
  }
}

// ---------------------------------------------------------------- embedding gather
__global__ void gather_x0(const int* __restrict__ text, const float* __restrict__ emb,
                          float* __restrict__ X0)
{
  const int b = blockIdx.x*256 + threadIdx.x;
  const int l = blockIdx.y, j = blockIdx.z;
  const int s = j*TL_ + l;
  const int row = text[(long long)s*B_ + b];
  const float* er = emb + (long long)row*E_;
  float* xp = X0 + ((long long)j*E_*TL_ + l)*B_ + b;
  for (int e = 0; e < E_; ++e) xp[(long long)e*TL_*B_] = er[e];
}

// ---------------------------------------------------------------- fp32 tiled GEMM (small mats: M/U/H)
template<bool CC, bool ADD_BIAS, bool ACCUM, bool OUT_LEAKY>
__global__ __launch_bounds__(256) void gemm_k(
    const float* __restrict__ A, long long aZ,
    const float* __restrict__ X, long long xZ,
    const float* __restrict__ X2,
    float* __restrict__ C, long long cZ,
    const float* __restrict__ bias, long long bZ,
    int K)
{
  const int z = blockIdx.z;
  A += (long long)z*aZ; X += (long long)z*xZ; C += (long long)z*cZ;
  const float* bz = ADD_BIAS ? bias + (long long)z*bZ : nullptr;

  const int f0 = blockIdx.x*64;
  const int b0 = blockIdx.y*64;
  const int tid = threadIdx.x;
  const int ty = tid >> 4, tx = tid & 15;

  __shared__ float As[32][64];
  __shared__ float Xs[32][64];

  float acc[4][4] = {};
  const int col = tid & 63, rr = tid >> 6;

  for (int k0 = 0; k0 < K; k0 += 32) {
    #pragma unroll
    for (int it = 0; it < 8; ++it) {
      const int kk = rr + it*4;
      const int k = k0 + kk;
      const int f = f0 + col;
      As[kk][col] = (k < K && f < F_) ? A[(long long)k*F_ + f] : 0.f;
      float v = 0.f;
      if (k < K) {
        if (CC && k >= F_) v = X2[(long long)(k - F_)*B_ + b0 + col];
        else               v = X [(long long)k*B_ + b0 + col];
      }
      Xs[kk][col] = v;
    }
    __syncthreads();
    #pragma unroll
    for (int kk = 0; kk < 32; ++kk) {
      const float4 a4 = *(const float4*)&As[kk][ty*4];
      const float4 x4 = *(const float4*)&Xs[kk][tx*4];
      const float aa[4] = {a4.x,a4.y,a4.z,a4.w};
      const float xx[4] = {x4.x,x4.y,x4.z,x4.w};
      #pragma unroll
      for (int i=0;i<4;i++)
        #pragma unroll
        for (int j=0;j<4;j++)
          acc[i][j] = fmaf(aa[i], xx[j], acc[i][j]);
    }
    __syncthreads();
  }

  #pragma unroll
  for (int i=0;i<4;i++) {
    const int f = f0 + ty*4 + i;
    if (f >= F_) continue;
    const long long base = (long long)f*B_ + b0 + tx*4;
    #pragma unroll
    for (int j=0;j<4;j++) {
      float v = acc[i][j];
      if (ADD_BIAS) v += bz[f];
      if (ACCUM) v += C[base + j];
      if (OUT_LEAKY) v = leaky_f(v);
      C[base + j] = v;
    }
  }
}

// ---------------------------------------------------------------- weight pack: W [F][K] -> frag [q][256][32] hi/lo
__global__ void pack_w(const float* __restrict__ W, int K, u16* __restrict__ Wh, u16* __restrict__ Wl)
{
  const int q = blockIdx.x;
  const int f = threadIdx.x;        // 256
  union { u16 u[32]; uint4 v[4]; } H, L;
  #pragma unroll
  for (int kk = 0; kk < 32; ++kk) {
    const int k = q*32 + kk;
    const float x = (k < K && f < F_) ? W[(size_t)f*K + k] : 0.f;
    const u16 h = bf16_rne(x);
    H.u[kk] = h;
    L.u[kk] = bf16_rne(x - bf16_to_f(h));
  }
  uint4* dh = (uint4*)(Wh + ((size_t)q*256 + f)*32);
  uint4* dl = (uint4*)(Wl + ((size_t)q*256 + f)*32);
  #pragma unroll
  for (int i = 0; i < 4; ++i) { dh[i] = H.v[i]; dl[i] = L.v[i]; }
}

// ---------------------------------------------------------------- activation pack (BN+leaky fused), per z, per col-chunk
// Y: [Cin][Lin][B] fp32. Out chunk: [q][CHUNK][32] hi/lo with global col c = cbase+local, c=(t,b).
template<bool BN, int KW>
__global__ void pack_act(const float* __restrict__ Y,
                         const float* __restrict__ bnS, const float* __restrict__ bnH,
                         u16* __restrict__ Ph, u16* __restrict__ Pl,
                         int K, int Lin, int cbase, int chunk)
{
  const int q = blockIdx.y;
  const int cl = blockIdx.x*256 + threadIdx.x;     // local col in chunk
  const int c = cbase + cl;
  const int t = c >> 11, b = c & 2047;
  union { u16 u[32]; uint4 v[4]; } H, L;
  #pragma unroll
  for (int kk = 0; kk < 32; ++kk) {
    const int k = q*32 + kk;
    float x = 0.f;
    if (k < K) {
      const int e = k / KW, kw = k - e*KW;
      x = Y[((size_t)e*Lin + (t + kw))*B_ + b];
      if (BN) { x = fmaf(x, bnS[e], bnH[e]); x = leaky_f(x); }
    }
    const u16 h = bf16_rne(x);
    H.u[kk] = h;
    L.u[kk] = bf16_rne(x - bf16_to_f(h));
  }
  uint4* dh = (uint4*)(Ph + ((size_t)q*chunk + cl)*32);
  uint4* dl = (uint4*)(Pl + ((size_t)q*chunk + cl)*32);
  #pragma unroll
  for (int i = 0; i < 4; ++i) { dh[i] = H.v[i]; dl[i] = L.v[i]; }
}

// ---------------------------------------------------------------- conv GEMM: pure streaming MFMA, per z, per col-chunk
template<bool OUT_LEAKY>
__global__ __launch_bounds__(256) void conv_gemm(
    const u16* __restrict__ Wh, const u16* __restrict__ Wl,
    const u16* __restrict__ Ph, const u16* __restrict__ Pl,
    const float* __restrict__ bias, float* __restrict__ C,
    int NQ, int cbase, int chunk, int Lout)
{
  const int c0l = blockIdx.x*64;
  const int w  = threadIdx.x >> 6;
  const int l  = threadIdx.x & 63;
  const int lr = l & 15, g = l >> 4;

  f32x4 acc[4][4] = {};

  for (int q = 0; q < NQ; ++q) {
    bf16x8 bh[4], bl[4];
    #pragma unroll
    for (int nt = 0; nt < 4; ++nt) {
      const size_t off = ((size_t)q*chunk + (c0l + nt*16 + lr))*32 + g*8;
      bh[nt] = *(const bf16x8*)(Ph + off);
      bl[nt] = *(const bf16x8*)(Pl + off);
    }
    #pragma unroll
    for (int mt = 0; mt < 4; ++mt) {
      const size_t woff = ((size_t)q*256 + (w*64 + mt*16 + lr))*32 + g*8;
      const bf16x8 ah = *(const bf16x8*)(Wh + woff);
      const bf16x8 al = *(const bf16x8*)(Wl + woff);
      #pragma unroll
      for (int nt = 0; nt < 4; ++nt) {
        acc[mt][nt] = __builtin_amdgcn_mfma_f32_16x16x32_bf16(ah, bh[nt], acc[mt][nt], 0, 0, 0);
        acc[mt][nt] = __builtin_amdgcn_mfma_f32_16x16x32_bf16(ah, bl[nt], acc[mt][nt], 0, 0, 0);
        acc[mt][nt] = __builtin_amdgcn_mfma_f32_16x16x32_bf16(al, bh[nt], acc[mt][nt], 0, 0, 0);
      }
    }
  }

  #pragma unroll
  for (int mt = 0; mt < 4; ++mt)
    #pragma unroll
    for (int j = 0; j < 4; ++j) {
      const int f = w*64 + mt*16 + g*4 + j;
      if (f < F_) {
        const float bs = bias[f];
        #pragma unroll
        for (int nt = 0; nt < 4; ++nt) {
          const int col = cbase + c0l + nt*16 + lr;
          const int t = col >> 11, b = col & 2047;
          float v = acc[mt][nt][j] + bs;
          if (OUT_LEAKY) v = leaky_f(v);
          C[((size_t)f*Lout + t)*B_ + b] = v;
        }
      }
    }
}

// ---------------------------------------------------------------- BN stats
__global__ void bn_stats(const float* __restrict__ Y, int L,
                         const float* __restrict__ gamma, const float* __restrict__ beta,
                         float* __restrict__ scale, float* __restrict__ shift)
{
  const int f = blockIdx.x, j = blockIdx.y;
  const float* p = Y + ((long long)(j*F_ + f))*L*B_;
  const int N = L*B_;
  double s = 0.0, s2 = 0.0;
  for (int i = threadIdx.x; i < N; i += 256) { double x = p[i]; s += x; s2 += x*x; }
  __shared__ double sh1[256], sh2[256];
  sh1[threadIdx.x] = s; sh2[threadIdx.x] = s2;
  __syncthreads();
  for (int off = 128; off; off >>= 1) {
    if (threadIdx.x < off) { sh1[threadIdx.x] += sh1[threadIdx.x+off]; sh2[threadIdx.x] += sh2[threadIdx.x+off]; }
    __syncthreads();
  }
  if (threadIdx.x == 0) {
    const double mean = sh1[0]/N;
    const double var  = sh2[0]/N - mean*mean;
    const float rstd = rsqrtf((float)var + EPS_);
    const float sc = gamma[f]*rstd;
    scale[j*F_+f] = sc;
    shift[j*F_+f] = beta[f] - (float)mean*sc;
  }
}

// ---------------------------------------------------------------- u_steps build
__global__ void us_build(const float* __restrict__ Uh, float* __restrict__ US)
{
  const long long i = (long long)blockIdx.x*256 + threadIdx.x;
  const long long FB = (long long)F_*B_;
  const int t = (int)(i / FB);
  const long long rem = i % FB;
  const int src = (t == 0) ? 6 : t;
  const float v = Uh[(long long)src*FB + rem];
  US[i] = (t < 5) ? leaky_f(v) : v;
}

// ---------------------------------------------------------------- fused scan step (MFMA): r-GEMM + finish + repack
__global__ __launch_bounds__(256) void r_step(
    const u16* __restrict__ RWh, const u16* __restrict__ RWl,
    const u16* __restrict__ Ain_h, const u16* __restrict__ Ain_l,
    const float* __restrict__ Rb, const float* __restrict__ XwT,
    const float* __restrict__ Xb, const float* __restrict__ HTt,
    const int* __restrict__ wprev,
    float* __restrict__ rn, u16* __restrict__ Ahi, u16* __restrict__ Alo)
{
  const int f0 = blockIdx.x*64;
  const int b0 = blockIdx.y*64;
  const int tid = threadIdx.x;
  const int w = tid >> 6, l = tid & 63;
  const int lr = l & 15, g = l >> 4;

  __shared__ float T[64][65];

  f32x4 acc[4] = {};
  for (int q = 0; q < KQ_; ++q) {
    const size_t aoff = ((size_t)q*256 + (f0 + w*16 + lr))*32 + g*8;
    const bf16x8 ah = *(const bf16x8*)(RWh + aoff);
    const bf16x8 al = *(const bf16x8*)(RWl + aoff);
    #pragma unroll
    for (int nt = 0; nt < 4; ++nt) {
      const size_t boff = ((size_t)q*B_ + (b0 + nt*16 + lr))*32 + g*8;
      const bf16x8 bh = *(const bf16x8*)(Ain_h + boff);
      const bf16x8 bl = *(const bf16x8*)(Ain_l + boff);
      acc[nt] = __builtin_amdgcn_mfma_f32_16x16x32_bf16(ah, bh, acc[nt], 0, 0, 0);
      acc[nt] = __builtin_amdgcn_mfma_f32_16x16x32_bf16(ah, bl, acc[nt], 0, 0, 0);
      acc[nt] = __builtin_amdgcn_mfma_f32_16x16x32_bf16(al, bh, acc[nt], 0, 0, 0);
    }
  }
  #pragma unroll
  for (int nt = 0; nt < 4; ++nt)
    #pragma unroll
    for (int j = 0; j < 4; ++j)
      T[w*16 + g*4 + j][nt*16 + lr] = acc[nt][j];
  __syncthreads();

  // epilogue: thread (ty,tx) owns cells (ty*4+i, tx*4+j)
  const int ty = tid >> 4, tx = tid & 15;
  int wv[4];
  #pragma unroll
  for (int j = 0; j < 4; ++j) {
    int t_ = wprev[b0 + tx*4 + j];
    wv[j] = (t_ < 0) ? 0 : (t_ >= V_ ? V_-1 : t_);   // safety clamp (no-op when correct)
  }

  #pragma unroll
  for (int i = 0; i < 4; ++i) {
    const int f = f0 + ty*4 + i;
    if (f < F_) {
      const float rb = Rb[f] + Xb[f];
      #pragma unroll
      for (int j = 0; j < 4; ++j) {
        const int b = b0 + tx*4 + j;
        float v = T[ty*4 + i][tx*4 + j] + rb + XwT[(size_t)wv[j]*F_ + f] + HTt[(size_t)f*B_ + b];
        v = leaky_f(v);
        rn[(size_t)f*B_ + b] = v;
        T[ty*4 + i][tx*4 + j] = v;
      }
    } else {
      #pragma unroll
      for (int j = 0; j < 4; ++j) T[ty*4 + i][tx*4 + j] = 0.f;
    }
  }
  __syncthreads();

  // repack this block's 64 fo-rows (2 k-chunks) into A-frag layout [q][b][32]
  const int bcol = tid & 63;
  const int kk0 = (tid >> 6)*8;
  #pragma unroll
  for (int qh = 0; qh < 2; ++qh) {
    const int q = (f0 >> 5) + qh;
    if (q >= KQ_) continue;
    union { u16 u[8]; uint4 v2[1]; } H, L;
    #pragma unroll
    for (int u = 0; u < 8; ++u) {
      const float x = T[qh*32 + kk0 + u][bcol];
      const u16 h = bf16_rne(x);
      H.u[u] = h;
      L.u[u] = bf16_rne(x - bf16_to_f(h));
    }
    const size_t off = ((size_t)q*B_ + b0 + bcol)*32 + kk0;
    *(uint4*)(Ahi + off) = H.v2[0];
    *(uint4*)(Alo + off) = L.v2[0];
  }
}

// ---------------------------------------------------------------- pack Yw into MFMA B-frag order (once, from [V][F])
__global__ void pack_yw(const float* __restrict__ Yw, u16* __restrict__ Bhi, u16* __restrict__ Blo)
{
  const int q = blockIdx.x;
  const int v = blockIdx.y*256 + threadIdx.x;
  if (v >= V_) return;
  union { u16 u[32]; uint4 w[4]; } H, L;
  #pragma unroll
  for (int kk = 0; kk < 32; ++kk) {
    const int f = q*32 + kk;
    const float x = (f < F_) ? Yw[(size_t)v*F_ + f] : 0.f;
    const u16 h = bf16_rne(x);
    H.u[kk] = h;
    L.u[kk] = bf16_rne(x - bf16_to_f(h));
  }
  uint4* dh = (uint4*)(Bhi + ((size_t)q*V_ + v)*32);
  uint4* dl = (uint4*)(Blo + ((size_t)q*V_ + v)*32);
  #pragma unroll
  for (int i = 0; i < 4; ++i) { dh[i] = H.w[i]; dl[i] = L.w[i]; }
}

// ---------------------------------------------------------------- MFMA Y-GEMM + online softmax partials
__global__ __launch_bounds__(256) void y_mfma(
    const u16* __restrict__ Ahi, const u16* __restrict__ Alo,
    const u16* __restrict__ Bhi, const u16* __restrict__ Blo,
    const float* __restrict__ Yb,
    float* __restrict__ pm, float* __restrict__ ps,
    float* __restrict__ pav, int* __restrict__ pai)
{
  const int vb = blockIdx.x;
  const int v0 = vb*64;
  const int b0 = blockIdx.y*128;
  const int w  = threadIdx.x >> 6;
  const int l  = threadIdx.x & 63;
  const int lr = l & 15;
  const int g  = l >> 4;

  f32x4 acc[2][4] = {};

  for (int q = 0; q < KQ_; ++q) {
    bf16x8 a_h[2], a_l[2], b_h[4], b_l[4];
    #pragma unroll
    for (int mt = 0; mt < 2; ++mt) {
      const int row = b0 + w*32 + mt*16 + lr;
      const size_t off = ((size_t)(q*B_ + row))*32 + g*8;
      a_h[mt] = *(const bf16x8*)(Ahi + off);
      a_l[mt] = *(const bf16x8*)(Alo + off);
    }
    #pragma unroll
    for (int nt = 0; nt < 4; ++nt) {
      const int col = v0 + nt*16 + lr;
      if (col < V_) {
        const size_t off = ((size_t)(q*V_ + col))*32 + g*8;
        b_h[nt] = *(const bf16x8*)(Bhi + off);
        b_l[nt] = *(const bf16x8*)(Blo + off);
      } else {
        b_h[nt] = (bf16x8)0; b_l[nt] = (bf16x8)0;
      }
    }
    #pragma unroll
    for (int mt = 0; mt < 2; ++mt)
      #pragma unroll
      for (int nt = 0; nt < 4; ++nt) {
        acc[mt][nt] = __builtin_amdgcn_mfma_f32_16x16x32_bf16(a_h[mt], b_h[nt], acc[mt][nt], 0, 0, 0);
        acc[mt][nt] = __builtin_amdgcn_mfma_f32_16x16x32_bf16(a_h[mt], b_l[nt], acc[mt][nt], 0, 0, 0);
        acc[mt][nt] = __builtin_amdgcn_mfma_f32_16x16x32_bf16(a_l[mt], b_h[nt], acc[mt][nt], 0, 0, 0);
      }
  }

  float m[2][4], ssum[2][4], av[2][4]; int ai[2][4];
  #pragma unroll
  for (int mt = 0; mt < 2; ++mt)
    #pragma unroll
    for (int j = 0; j < 4; ++j) { m[mt][j] = -INFINITY; ssum[mt][j] = 0.f; av[mt][j] = -INFINITY; ai[mt][j] = 0x7fffffff; }

  #pragma unroll
  for (int nt = 0; nt < 4; ++nt) {
    const int colv = v0 + nt*16 + lr;
    if (colv >= V_) continue;
    const float yb = Yb[colv];
    #pragma unroll
    for (int mt = 0; mt < 2; ++mt)
      #pragma unroll
      for (int j = 0; j < 4; ++j) {
        const float y = acc[mt][nt][j] + yb;
        if (y > av[mt][j]) { av[mt][j] = y; ai[mt][j] = colv; }
        if (y <= m[mt][j]) ssum[mt][j] += __expf(y - m[mt][j]);
        else { ssum[mt][j] = ssum[mt][j]*__expf(m[mt][j]-y) + 1.f; m[mt][j] = y; }
      }
  }

  #pragma unroll
  for (int off = 1; off <= 8; off <<= 1) {
    #pragma unroll
    for (int mt = 0; mt < 2; ++mt)
      #pragma unroll
      for (int j = 0; j < 4; ++j) {
        const float om = __shfl_xor(m[mt][j], off);
        const float os = __shfl_xor(ssum[mt][j], off);
        const float M2 = fmaxf(m[mt][j], om);
        if (M2 == -INFINITY) { ssum[mt][j] = 0.f; }
        else {
          const float t1 = (m[mt][j] == -INFINITY) ? 0.f : ssum[mt][j]*__expf(m[mt][j]-M2);
          const float t2 = (om       == -INFINITY) ? 0.f : os        *__expf(om      -M2);
          ssum[mt][j] = t1 + t2;
        }
        m[mt][j] = M2;
        const float oav = __shfl_xor(av[mt][j], off);
        const int   oai = __shfl_xor(ai[mt][j], off);
        if (oav > av[mt][j] || (oav == av[mt][j] && oai < ai[mt][j])) { av[mt][j] = oav; ai[mt][j] = oai; }
      }
  }

  if (lr == 0) {
    #pragma unroll
    for (int mt = 0; mt < 2; ++mt)
      #pragma unroll
      for (int j = 0; j < 4; ++j) {
        const int row = b0 + w*32 + mt*16 + g*4 + j;
        const size_t idx = (size_t)row*NVB + vb;
        pm[idx] = m[mt][j]; ps[idx] = ssum[mt][j];
        pav[idx] = av[mt][j]; pai[idx] = ai[mt][j];
      }
  }
}

// ---------------------------------------------------------------- combine partials + exact fp32 target logit
__global__ void combine2(const float* __restrict__ pm, const float* __restrict__ ps,
                         const float* __restrict__ pav, const int* __restrict__ pai,
                         const float* __restrict__ r, const float* __restrict__ Yw,
                         const float* __restrict__ Yb, const int* __restrict__ tgt,
                         int* __restrict__ w, float* __restrict__ loss_row,
                         int* __restrict__ corr_row)
{
  const int b = blockIdx.x;
  const int lane = threadIdx.x;      // 64
  const int tb = tgt[b];

  float td = 0.f;
  #pragma unroll
  for (int it = 0; it < 4; ++it) {
    const int f = lane + it*64;
    if (f < F_) td = fmaf(r[(size_t)f*B_ + b], Yw[(size_t)tb*F_ + f], td);
  }

  float M = -INFINITY, S = 0.f, av = -INFINITY; int ai = 0x7fffffff;
  for (int p = lane; p < NVB; p += 64) {
    const size_t idx = (size_t)b*NVB + p;
    const float mm = pm[idx], s = ps[idx];
    const float M2 = fmaxf(M, mm);
    if (M2 == -INFINITY) { S = 0.f; }
    else {
      const float t1 = (M  == -INFINITY) ? 0.f : S*__expf(M  - M2);
      const float t2 = (mm == -INFINITY) ? 0.f : s*__expf(mm - M2);
      S = t1 + t2;
    }
    M = M2;
    const float v = pav[idx]; const int iidx = pai[idx];
    if (v > av || (v == av && iidx < ai)) { av = v; ai = iidx; }
  }
  #pragma unroll
  for (int off = 1; off <= 32; off <<= 1) {
    td += __shfl_xor(td, off);
    const float om = __shfl_xor(M, off);
    const float os = __shfl_xor(S, off);
    const float M2 = fmaxf(M, om);
    if (M2 == -INFINITY) { S = 0.f; }
    else {
      const float t1 = (M  == -INFINITY) ? 0.f : S *__expf(M  - M2);
      const float t2 = (om == -INFINITY) ? 0.f : os*__expf(om - M2);
      S = t1 + t2;
    }
    M = M2;
    const float oav = __shfl_xor(av, off);
    const int   oai = __shfl_xor(ai, off);
    if (oav > av || (oav == av && oai < ai)) { av = oav; ai = oai; }
  }
  if (lane == 0) {
    const float logZ = M + logf(S);
    loss_row[b] = logZ - (td + Yb[tb]);
    corr_row[b] = (ai == tb) ? 1 : 0;
    w[b] = ai;
  }
}

// ---------------------------------------------------------------- final deterministic reduce
__global__ void finalize_k(const float* __restrict__ lr, const int* __restrict__ cr,
                           float* __restrict__ out)
{
  __shared__ float sf[256]; __shared__ int si[256];
  float s = 0.f; int c = 0;
  for (int i = threadIdx.x; i < 7*B_; i += 256) { s += lr[i]; c += cr[i]; }
  sf[threadIdx.x] = s; si[threadIdx.x] = c;
  __syncthreads();
  for (int off = 128; off; off >>= 1) {
    if (threadIdx.x < off) { sf[threadIdx.x] += sf[threadIdx.x+off]; si[threadIdx.x] += si[threadIdx.x+off]; }
    __syncthreads();
  }
  if (threadIdx.x == 0) { out[0] = sf[0] / (float)B_; out[1] = (float)si[0]; }
}

// ================================================================ host
extern "C" void kernel_launch(void* const* d_in, const int* in_sizes, int n_in,
                              void* d_out, int out_size, void* d_ws, size_t ws_size,
                              hipStream_t stream)
{
  (void)in_sizes; (void)n_in; (void)out_size; (void)ws_size;
  const int*   text = (const int*)d_in[0];
  const float* emb  = (const float*)d_in[3];
  const float* gamma= (const float*)d_in[4];
  const float* beta = (const float*)d_in[5];
  const float* c1w = (const float*)d_in[6];  const float* c1b = (const float*)d_in[7];
  const float* c2w = (const float*)d_in[8];  const float* c2b = (const float*)d_in[9];
  const float* c3w = (const float*)d_in[10]; const float* c3b = (const float*)d_in[11];
  const float* c4w = (const float*)d_in[12]; const float* c4b = (const float*)d_in[13];
  const float* Mw = (const float*)d_in[14];  const float* Mb = (const float*)d_in[15];
  const float* Uw = (const float*)d_in[16];  const float* Ub = (const float*)d_in[17];
  const float* Rw = (const float*)d_in[18];  const float* Rb = (const float*)d_in[19];
  const float* Hw = (const float*)d_in[20];  const float* Hb = (const float*)d_in[21];
  const float* Xw = (const float*)d_in[22];  const float* Xb = (const float*)d_in[23];
  const float* Yw = (const float*)d_in[24];  const float* Yb = (const float*)d_in[25];

  float* ws = (float*)d_ws;
  size_t off = 0;
  auto alloc = [&](size_t n)->float* { float* p = ws + off; off += (n + 63) & ~(size_t)63; return p; };

  float* WT_M  = alloc(400*F_);
  float* WT_U  = alloc((size_t)7*F_*F_);
  float* WT_H  = alloc((size_t)F_*F_);
  // packed weights: [NQ][256][32] u16 hi/lo
  u16* W1h = (u16*)alloc((size_t)10*256*32/2); u16* W1l = (u16*)alloc((size_t)10*256*32/2);
  u16* W2h = (u16*)alloc((size_t)13*256*32/2); u16* W2l = (u16*)alloc((size_t)13*256*32/2);
  u16* W3h = (u16*)alloc((size_t)19*256*32/2); u16* W3l = (u16*)alloc((size_t)19*256*32/2);
  u16* W4h = (u16*)alloc((size_t)19*256*32/2); u16* W4l = (u16*)alloc((size_t)19*256*32/2);
  u16* RWh = (u16*)alloc((size_t)7*256*32/2);  u16* RWl = (u16*)alloc((size_t)7*256*32/2);
  float* S1 = alloc(3*F_); float* Sh1 = alloc(3*F_);
  float* S2 = alloc(3*F_); float* Sh2 = alloc(3*F_);
  float* S3 = alloc(3*F_); float* Sh3 = alloc(3*F_);
  float* P  = alloc((size_t)NSEG_*E_*TL_*B_);     // X0 -> Y2 -> HT + packed planes
  float* Q  = alloc((size_t)NSEG_*F_*6*B_);       // Y1 -> Y3 -> Uh+US -> partials + XwT
  float* VEC = alloc((size_t)NSEG_*F_*B_);
  float* hA = alloc((size_t)F_*B_);
  float* hB = alloc((size_t)F_*B_);
  float* rA = alloc((size_t)F_*B_);
  // activation pack buffer (per z, per col-chunk). Max chunk need: conv2 half = 13*5120*32 u16
  u16* PKh = (u16*)alloc((size_t)13*5120*32/2);
  u16* PKl = (u16*)alloc((size_t)13*5120*32/2);
  int*   wbuf = (int*)alloc(B_);
  float* loss_rows = alloc((size_t)7*B_);
  int*   corr_rows = (int*)alloc((size_t)7*B_);

  float* X0 = P;                                   // [3][150][7][B]
  float* Y1 = Q;                                   // [3][200][6][B]
  float* Y2 = P;                                   // [3][200][5][B]
  float* Y3 = Q;                                   // [3][200][3][B]
  float* Uh = Q;                                   // [7][200][B]
  float* US = Q + (size_t)7*F_*B_;                 // [7][200][B]
  float* HT = P;                                   // [7][200][B] live through scan

  const size_t HT_FL = (size_t)7*F_*B_;            // 2,867,200 floats (mult of 64)
  u16* YWhi = (u16*)(P + HT_FL);
  u16* YWlo = YWhi + (size_t)KQ_*V_*32;            // 2,240,000 u16 each
  u16* A0h  = YWlo + (size_t)KQ_*V_*32;
  u16* A0l  = A0h + (size_t)KQ_*B_*32;             // 458,752 u16 each
  u16* A1h  = A0l + (size_t)KQ_*B_*32;
  u16* A1l  = A1h + (size_t)KQ_*B_*32;
  // tail ends at P + 6,024,704 <= 6,451,200 OK

  float* pm  = Q;                                  // scan partials (Uh/US dead)
  float* ps2 = Q + (size_t)B_*NVB;
  float* pav = Q + (size_t)2*B_*NVB;
  int*   pai = (int*)(Q + (size_t)3*B_*NVB);
  float* XwT = Q + (size_t)2097152;                // [V][F] = 2,000,000 fl, ends 4,097,152 <= Q size

  const dim3 tb_(32,8);
  hipLaunchKernelGGL(transpose_k, dim3(13,7,1),  tb_, 0, stream, Mw,  WT_M,  F_, 400);
  hipLaunchKernelGGL(transpose_k, dim3(7,7,7),   tb_, 0, stream, Uw,  WT_U,  F_, F_);
  hipLaunchKernelGGL(transpose_k, dim3(7,7,1),   tb_, 0, stream, Hw,  WT_H,  F_, F_);

  hipLaunchKernelGGL(pack_w, dim3(10), dim3(256), 0, stream, c1w, 300, W1h, W1l);
  hipLaunchKernelGGL(pack_w, dim3(13), dim3(256), 0, stream, c2w, 400, W2h, W2l);
  hipLaunchKernelGGL(pack_w, dim3(19), dim3(256), 0, stream, c3w, 600, W3h, W3l);
  hipLaunchKernelGGL(pack_w, dim3(19), dim3(256), 0, stream, c4w, 600, W4h, W4l);
  hipLaunchKernelGGL(pack_w, dim3(7),  dim3(256), 0, stream, Rw,  200, RWh, RWl);

  hipMemsetAsync(hA,   0, (size_t)F_*B_*4, stream);
  hipMemsetAsync(wbuf, 0, (size_t)B_*4,    stream);

  hipLaunchKernelGGL(gather_x0, dim3(B_/256, TL_, NSEG_), dim3(256), 0, stream, text, emb, X0);

  // ---- conv stack (per-z, per-col-chunk pack + streaming MFMA GEMM) ----
  for (int z = 0; z < NSEG_; ++z)
    for (int hcol = 0; hcol < 2; ++hcol) {
      const int cb = hcol*6144;
      hipLaunchKernelGGL((pack_act<false,2>), dim3(24,10), dim3(256), 0, stream,
          X0 + (size_t)z*E_*TL_*B_, nullptr, nullptr, PKh, PKl, 300, TL_, cb, 6144);
      hipLaunchKernelGGL((conv_gemm<false>), dim3(96), dim3(256), 0, stream,
          W1h, W1l, PKh, PKl, c1b, Y1 + (size_t)z*F_*6*B_, 10, cb, 6144, 6);
    }
  hipLaunchKernelGGL(bn_stats, dim3(F_, NSEG_), dim3(256), 0, stream, Y1, 6, gamma, beta, S1, Sh1);
  for (int z = 0; z < NSEG_; ++z)
    for (int hcol = 0; hcol < 2; ++hcol) {
      const int cb = hcol*5120;
      hipLaunchKernelGGL((pack_act<true,2>), dim3(20,13), dim3(256), 0, stream,
          Y1 + (size_t)z*F_*6*B_, S1 + z*F_, Sh1 + z*F_, PKh, PKl, 400, 6, cb, 5120);
      hipLaunchKernelGGL((conv_gemm<false>), dim3(80), dim3(256), 0, stream,
          W2h, W2l, PKh, PKl, c2b, Y2 + (size_t)z*F_*5*B_, 13, cb, 5120, 5);
    }
  hipLaunchKernelGGL(bn_stats, dim3(F_, NSEG_), dim3(256), 0, stream, Y2, 5, gamma, beta, S2, Sh2);
  for (int z = 0; z < NSEG_; ++z)
    for (int hcol = 0; hcol < 2; ++hcol) {
      const int cb = hcol*3072;
      hipLaunchKernelGGL((pack_act<true,3>), dim3(12,19), dim3(256), 0, stream,
          Y2 + (size_t)z*F_*5*B_, S2 + z*F_, Sh2 + z*F_, PKh, PKl, 600, 5, cb, 3072);
      hipLaunchKernelGGL((conv_gemm<false>), dim3(48), dim3(256), 0, stream,
          W3h, W3l, PKh, PKl, c3b, Y3 + (size_t)z*F_*3*B_, 19, cb, 3072, 3);
    }
  hipLaunchKernelGGL(bn_stats, dim3(F_, NSEG_), dim3(256), 0, stream, Y3, 3, gamma, beta, S3, Sh3);
  for (int z = 0; z < NSEG_; ++z) {
    hipLaunchKernelGGL((pack_act<true,3>), dim3(8,19), dim3(256), 0, stream,
        Y3 + (size_t)z*F_*3*B_, S3 + z*F_, Sh3 + z*F_, PKh, PKl, 600, 3, 0, 2048);
    hipLaunchKernelGGL((conv_gemm<true>), dim3(32), dim3(256), 0, stream,
        W4h, W4l, PKh, PKl, c4b, VEC + (size_t)z*F_*B_, 19, 0, 2048, 1);
  }

  // ---- M chain (fused concat) ----
  float* hc = hA; float* hn = hB;
  for (int i = 0; i < 3; ++i) {
    hipLaunchKernelGGL((gemm_k<true,true,false,true>), dim3(4, NB64, 1), dim3(256), 0, stream,
        WT_M, 0, VEC + (size_t)i*F_*B_, 0, hc, hn, 0, Mb, 0, 400);
    float* t_ = hc; hc = hn; hn = t_;
  }

  // ---- U / us / H ----
  hipLaunchKernelGGL((gemm_k<false,true,false,false>), dim3(4, NB64, 6), dim3(256), 0, stream,
      WT_U + (size_t)F_*F_, (long long)F_*F_, hc, 0, nullptr, Uh + (size_t)F_*B_, (long long)F_*B_,
      Ub + F_, F_, 200);
  hipLaunchKernelGGL(us_build, dim3(7*F_*B_/256), dim3(256), 0, stream, Uh, US);
  hipLaunchKernelGGL((gemm_k<false,true,false,false>), dim3(4, NB64, 7), dim3(256), 0, stream,
      WT_H, 0, US, (long long)F_*B_, nullptr, HT, (long long)F_*B_, Hb, 0, 200);

  // ---- scan prep: XwT transpose + Yw pack + A0 zero (AFTER P-tail stops being clobbered) ----
  hipLaunchKernelGGL(transpose_k, dim3(313,7,1), tb_, 0, stream, Xw, XwT, F_, V_);
  hipLaunchKernelGGL(pack_yw, dim3(KQ_, (V_+255)/256), dim3(256), 0, stream, Yw, YWhi, YWlo);
  hipMemsetAsync(A0h, 0, (size_t)2*KQ_*B_*32*2, stream);   // A0h + A0l (contiguous), zero r0 frags

  // ---- scan ----
  u16 *cin_h = A0h, *cin_l = A0l, *cout_h = A1h, *cout_l = A1l;
  for (int t = 0; t < 7; ++t) {
    hipLaunchKernelGGL(r_step, dim3(4, 32), dim3(256), 0, stream,
        RWh, RWl, cin_h, cin_l, Rb, XwT, Xb, HT + (size_t)t*F_*B_, wbuf, rA, cout_h, cout_l);
    hipLaunchKernelGGL(y_mfma, dim3(NVB, B_/128), dim3(256), 0, stream,
        cout_h, cout_l, YWhi, YWlo, Yb, pm, ps2, pav, pai);
    const int* tgt_t = text + (size_t)(21 + t)*B_;
    hipLaunchKernelGGL(combine2, dim3(B_), dim3(64), 0, stream,
        pm, ps2, pav, pai, rA, Yw, Yb, tgt_t, wbuf, loss_rows + (size_t)t*B_, corr_rows + (size_t)t*B_);
    u16* th = cin_h; cin_h = cout_h; cout_h = th;
    u16* tl = cin_l; cin_l = cout_l; cout_l = tl;
  }

  hipLaunchKernelGGL(finalize_k, dim3(1), dim3(256), 0, stream, loss_rows, corr_rows, (float*)d_out);
}

// Round 7
// 1514.676 us; speedup vs baseline: 1.2182x; 1.2182x over previous
//
#include <hip/hip_runtime.h>
#include <math.h>

#define V_    10000
#define E_    150
#define F_    200
#define TL_   7
#define B_    2048
#define NSEG_ 3
#define EPS_  1e-5f
#define SLOPE_ 0.01f
#define NB64  (B_/64)
#define NVB   157          // ceil(10000/64) v-parts for MFMA Y-GEMM
#define NYB   2560         // 8 xcd * 20 vb-slots * 16 b-tiles
#define KQ_   7            // K chunks of 32 for F_=200 (padded 224)

typedef unsigned short u16;
typedef __attribute__((ext_vector_type(8))) short bf16x8;
typedef __attribute__((ext_vector_type(4))) float f32x4;

__device__ __forceinline__ float leaky_f(float x){ return x >= 0.f ? x : SLOPE_*x; }
__device__ __forceinline__ u16 bf16_rne(float x){
  unsigned u = __float_as_uint(x);
  unsigned r = (u + 0x7FFFu + ((u>>16)&1u)) >> 16;
  return (u16)r;
}
__device__ __forceinline__ float bf16_to_f(u16 h){ return __uint_as_float(((unsigned)h)<<16); }

// ---------------------------------------------------------------- transpose
__global__ void transpose_k(const float* __restrict__ in, float* __restrict__ out,
                            int R, int C)
{
  __shared__ float tile[32][33];
  const long long bofs = (long long)blockIdx.z * R * C;
  in += bofs; out += bofs;
  const int c0 = blockIdx.x*32, r0 = blockIdx.y*32;
  const int tx = threadIdx.x, ty = threadIdx.y;  // (32,8)
  for (int i = ty; i < 32; i += 8) {
    int r = r0 + i, c = c0 + tx;
    if (r < R && c < C) tile[i][tx] = in[(long long)r*C + c];
  }
  __syncthreads();
  for (int i = ty; i < 32; i += 8) {
    int c = c0 + i, r = r0 + tx;
    if (c < C && r < R) out[(long long)c*R + r] = tile[tx][i];
  }
}

// ---------------------------------------------------------------- embedding gather
__global__ void gather_x0(const int* __restrict__ text, const float* __restrict__ emb,
                          float* __restrict__ X0)
{
  const int b = blockIdx.x*256 + threadIdx.x;
  const int l = blockIdx.y, j = blockIdx.z;
  const int s = j*TL_ + l;
  const int row = text[(long long)s*B_ + b];
  const float* er = emb + (long long)row*E_;
  float* xp = X0 + ((long long)j*E_*TL_ + l)*B_ + b;
  for (int e = 0; e < E_; ++e) xp[(long long)e*TL_*B_] = er[e];
}

// ---------------------------------------------------------------- fp32 tiled GEMM (small mats: M/U/H)
template<bool CC, bool ADD_BIAS, bool ACCUM, bool OUT_LEAKY>
__global__ __launch_bounds__(256) void gemm_k(
    const float* __restrict__ A, long long aZ,
    const float* __restrict__ X, long long xZ,
    const float* __restrict__ X2,
    float* __restrict__ C, long long cZ,
    const float* __restrict__ bias, long long bZ,
    int K)
{
  const int z = blockIdx.z;
  A += (long long)z*aZ; X += (long long)z*xZ; C += (long long)z*cZ;
  const float* bz = ADD_BIAS ? bias + (long long)z*bZ : nullptr;

  const int f0 = blockIdx.x*64;
  const int b0 = blockIdx.y*64;
  const int tid = threadIdx.x;
  const int ty = tid >> 4, tx = tid & 15;

  __shared__ float As[32][64];
  __shared__ float Xs[32][64];

  float acc[4][4] = {};
  const int col = tid & 63, rr = tid >> 6;

  for (int k0 = 0; k0 < K; k0 += 32) {
    #pragma unroll
    for (int it = 0; it < 8; ++it) {
      const int kk = rr + it*4;
      const int k = k0 + kk;
      const int f = f0 + col;
      As[kk][col] = (k < K && f < F_) ? A[(long long)k*F_ + f] : 0.f;
      float v = 0.f;
      if (k < K) {
        if (CC && k >= F_) v = X2[(long long)(k - F_)*B_ + b0 + col];
        else               v = X [(long long)k*B_ + b0 + col];
      }
      Xs[kk][col] = v;
    }
    __syncthreads();
    #pragma unroll
    for (int kk = 0; kk < 32; ++kk) {
      const float4 a4 = *(const float4*)&As[kk][ty*4];
      const float4 x4 = *(const float4*)&Xs[kk][tx*4];
      const float aa[4] = {a4.x,a4.y,a4.z,a4.w};
      const float xx[4] = {x4.x,x4.y,x4.z,x4.w};
      #pragma unroll
      for (int i=0;i<4;i++)
        #pragma unroll
        for (int j=0;j<4;j++)
          acc[i][j] = fmaf(aa[i], xx[j], acc[i][j]);
    }
    __syncthreads();
  }

  #pragma unroll
  for (int i=0;i<4;i++) {
    const int f = f0 + ty*4 + i;
    if (f >= F_) continue;
    const long long base = (long long)f*B_ + b0 + tx*4;
    #pragma unroll
    for (int j=0;j<4;j++) {
      float v = acc[i][j];
      if (ADD_BIAS) v += bz[f];
      if (ACCUM) v += C[base + j];
      if (OUT_LEAKY) v = leaky_f(v);
      C[base + j] = v;
    }
  }
}

// ---------------------------------------------------------------- weight pack: W [F][K] -> frag [q][256][32] hi/lo
__global__ void pack_w(const float* __restrict__ W, int K, u16* __restrict__ Wh, u16* __restrict__ Wl)
{
  const int q = blockIdx.x;
  const int f = threadIdx.x;        // 256
  union { u16 u[32]; uint4 v[4]; } H, L;
  #pragma unroll
  for (int kk = 0; kk < 32; ++kk) {
    const int k = q*32 + kk;
    const float x = (k < K && f < F_) ? W[(size_t)f*K + k] : 0.f;
    const u16 h = bf16_rne(x);
    H.u[kk] = h;
    L.u[kk] = bf16_rne(x - bf16_to_f(h));
  }
  uint4* dh = (uint4*)(Wh + ((size_t)q*256 + f)*32);
  uint4* dl = (uint4*)(Wl + ((size_t)q*256 + f)*32);
  #pragma unroll
  for (int i = 0; i < 4; ++i) { dh[i] = H.v[i]; dl[i] = L.v[i]; }
}

// ---------------------------------------------------------------- activation pack (BN+leaky fused), per z (full cols)
template<bool BN, int KW>
__global__ void pack_act(const float* __restrict__ Y,
                         const float* __restrict__ bnS, const float* __restrict__ bnH,
                         u16* __restrict__ Ph, u16* __restrict__ Pl,
                         int K, int Lin, int Ncols)
{
  const int q = blockIdx.y;
  const int c = blockIdx.x*256 + threadIdx.x;
  const int t = c >> 11, b = c & 2047;
  union { u16 u[32]; uint4 v[4]; } H, L;
  #pragma unroll
  for (int kk = 0; kk < 32; ++kk) {
    const int k = q*32 + kk;
    float x = 0.f;
    if (k < K) {
      const int e = k / KW, kw = k - e*KW;
      x = Y[((size_t)e*Lin + (t + kw))*B_ + b];
      if (BN) { x = fmaf(x, bnS[e], bnH[e]); x = leaky_f(x); }
    }
    const u16 h = bf16_rne(x);
    H.u[kk] = h;
    L.u[kk] = bf16_rne(x - bf16_to_f(h));
  }
  uint4* dh = (uint4*)(Ph + ((size_t)q*Ncols + c)*32);
  uint4* dl = (uint4*)(Pl + ((size_t)q*Ncols + c)*32);
  #pragma unroll
  for (int i = 0; i < 4; ++i) { dh[i] = H.v[i]; dl[i] = L.v[i]; }
}

// ---------------------------------------------------------------- conv GEMM: pure streaming MFMA, per z
template<bool OUT_LEAKY>
__global__ __launch_bounds__(256) void conv_gemm(
    const u16* __restrict__ Wh, const u16* __restrict__ Wl,
    const u16* __restrict__ Ph, const u16* __restrict__ Pl,
    const float* __restrict__ bias, float* __restrict__ C,
    int NQ, int Ncols, int Lout)
{
  const int c0 = blockIdx.x*64;
  const int w  = threadIdx.x >> 6;
  const int l  = threadIdx.x & 63;
  const int lr = l & 15, g = l >> 4;

  f32x4 acc[4][4] = {};

  for (int q = 0; q < NQ; ++q) {
    bf16x8 bh[4], bl[4];
    #pragma unroll
    for (int nt = 0; nt < 4; ++nt) {
      const size_t off = ((size_t)q*Ncols + (c0 + nt*16 + lr))*32 + g*8;
      bh[nt] = *(const bf16x8*)(Ph + off);
      bl[nt] = *(const bf16x8*)(Pl + off);
    }
    #pragma unroll
    for (int mt = 0; mt < 4; ++mt) {
      const size_t woff = ((size_t)q*256 + (w*64 + mt*16 + lr))*32 + g*8;
      const bf16x8 ah = *(const bf16x8*)(Wh + woff);
      const bf16x8 al = *(const bf16x8*)(Wl + woff);
      #pragma unroll
      for (int nt = 0; nt < 4; ++nt) {
        acc[mt][nt] = __builtin_amdgcn_mfma_f32_16x16x32_bf16(ah, bh[nt], acc[mt][nt], 0, 0, 0);
        acc[mt][nt] = __builtin_amdgcn_mfma_f32_16x16x32_bf16(ah, bl[nt], acc[mt][nt], 0, 0, 0);
        acc[mt][nt] = __builtin_amdgcn_mfma_f32_16x16x32_bf16(al, bh[nt], acc[mt][nt], 0, 0, 0);
      }
    }
  }

  #pragma unroll
  for (int mt = 0; mt < 4; ++mt)
    #pragma unroll
    for (int j = 0; j < 4; ++j) {
      const int f = w*64 + mt*16 + g*4 + j;
      if (f < F_) {
        const float bs = bias[f];
        #pragma unroll
        for (int nt = 0; nt < 4; ++nt) {
          const int col = c0 + nt*16 + lr;
          const int t = col >> 11, b = col & 2047;
          float v = acc[mt][nt][j] + bs;
          if (OUT_LEAKY) v = leaky_f(v);
          C[((size_t)f*Lout + t)*B_ + b] = v;
        }
      }
    }
}

// ---------------------------------------------------------------- BN stats
__global__ void bn_stats(const float* __restrict__ Y, int L,
                         const float* __restrict__ gamma, const float* __restrict__ beta,
                         float* __restrict__ scale, float* __restrict__ shift)
{
  const int f = blockIdx.x, j = blockIdx.y;
  const float* p = Y + ((long long)(j*F_ + f))*L*B_;
  const int N = L*B_;
  double s = 0.0, s2 = 0.0;
  for (int i = threadIdx.x; i < N; i += 256) { double x = p[i]; s += x; s2 += x*x; }
  __shared__ double sh1[256], sh2[256];
  sh1[threadIdx.x] = s; sh2[threadIdx.x] = s2;
  __syncthreads();
  for (int off = 128; off; off >>= 1) {
    if (threadIdx.x < off) { sh1[threadIdx.x] += sh1[threadIdx.x+off]; sh2[threadIdx.x] += sh2[threadIdx.x+off]; }
    __syncthreads();
  }
  if (threadIdx.x == 0) {
    const double mean = sh1[0]/N;
    const double var  = sh2[0]/N - mean*mean;
    const float rstd = rsqrtf((float)var + EPS_);
    const float sc = gamma[f]*rstd;
    scale[j*F_+f] = sc;
    shift[j*F_+f] = beta[f] - (float)mean*sc;
  }
}

// ---------------------------------------------------------------- u_steps build
__global__ void us_build(const float* __restrict__ Uh, float* __restrict__ US)
{
  const long long i = (long long)blockIdx.x*256 + threadIdx.x;
  const long long FB = (long long)F_*B_;
  const int t = (int)(i / FB);
  const long long rem = i % FB;
  const int src = (t == 0) ? 6 : t;
  const float v = Uh[(long long)src*FB + rem];
  US[i] = (t < 5) ? leaky_f(v) : v;
}

// ---------------------------------------------------------------- fused scan step (MFMA): r-GEMM + finish + repack
__global__ __launch_bounds__(256) void r_step(
    const u16* __restrict__ RWh, const u16* __restrict__ RWl,
    const u16* __restrict__ Ain_h, const u16* __restrict__ Ain_l,
    const float* __restrict__ Rb, const float* __restrict__ XwT,
    const float* __restrict__ Xb, const float* __restrict__ HTt,
    const int* __restrict__ wprev,
    float* __restrict__ rn, u16* __restrict__ Ahi, u16* __restrict__ Alo)
{
  const int f0 = blockIdx.x*64;
  const int b0 = blockIdx.y*64;
  const int tid = threadIdx.x;
  const int w = tid >> 6, l = tid & 63;
  const int lr = l & 15, g = l >> 4;

  __shared__ float T[64][65];

  f32x4 acc[4] = {};
  for (int q = 0; q < KQ_; ++q) {
    const size_t aoff = ((size_t)q*256 + (f0 + w*16 + lr))*32 + g*8;
    const bf16x8 ah = *(const bf16x8*)(RWh + aoff);
    const bf16x8 al = *(const bf16x8*)(RWl + aoff);
    #pragma unroll
    for (int nt = 0; nt < 4; ++nt) {
      const size_t boff = ((size_t)q*B_ + (b0 + nt*16 + lr))*32 + g*8;
      const bf16x8 bh = *(const bf16x8*)(Ain_h + boff);
      const bf16x8 bl = *(const bf16x8*)(Ain_l + boff);
      acc[nt] = __builtin_amdgcn_mfma_f32_16x16x32_bf16(ah, bh, acc[nt], 0, 0, 0);
      acc[nt] = __builtin_amdgcn_mfma_f32_16x16x32_bf16(ah, bl, acc[nt], 0, 0, 0);
      acc[nt] = __builtin_amdgcn_mfma_f32_16x16x32_bf16(al, bh, acc[nt], 0, 0, 0);
    }
  }
  #pragma unroll
  for (int nt = 0; nt < 4; ++nt)
    #pragma unroll
    for (int j = 0; j < 4; ++j)
      T[w*16 + g*4 + j][nt*16 + lr] = acc[nt][j];
  __syncthreads();

  // epilogue: thread (ty,tx) owns cells (ty*4+i, tx*4+j)
  const int ty = tid >> 4, tx = tid & 15;
  int wv[4];
  #pragma unroll
  for (int j = 0; j < 4; ++j) {
    int t_ = wprev[b0 + tx*4 + j];
    wv[j] = (t_ < 0) ? 0 : (t_ >= V_ ? V_-1 : t_);   // safety clamp (no-op when correct)
  }

  #pragma unroll
  for (int i = 0; i < 4; ++i) {
    const int f = f0 + ty*4 + i;
    if (f < F_) {
      const float rb = Rb[f] + Xb[f];
      #pragma unroll
      for (int j = 0; j < 4; ++j) {
        const int b = b0 + tx*4 + j;
        float v = T[ty*4 + i][tx*4 + j] + rb + XwT[(size_t)wv[j]*F_ + f] + HTt[(size_t)f*B_ + b];
        v = leaky_f(v);
        rn[(size_t)f*B_ + b] = v;
        T[ty*4 + i][tx*4 + j] = v;
      }
    } else {
      #pragma unroll
      for (int j = 0; j < 4; ++j) T[ty*4 + i][tx*4 + j] = 0.f;
    }
  }
  __syncthreads();

  // repack this block's 64 fo-rows (2 k-chunks) into A-frag layout [q][b][32]
  const int bcol = tid & 63;
  const int kk0 = (tid >> 6)*8;
  #pragma unroll
  for (int qh = 0; qh < 2; ++qh) {
    const int q = (f0 >> 5) + qh;
    if (q >= KQ_) continue;
    union { u16 u[8]; uint4 v2[1]; } H, L;
    #pragma unroll
    for (int u = 0; u < 8; ++u) {
      const float x = T[qh*32 + kk0 + u][bcol];
      const u16 h = bf16_rne(x);
      H.u[u] = h;
      L.u[u] = bf16_rne(x - bf16_to_f(h));
    }
    const size_t off = ((size_t)q*B_ + b0 + bcol)*32 + kk0;
    *(uint4*)(Ahi + off) = H.v2[0];
    *(uint4*)(Alo + off) = L.v2[0];
  }
}

// ---------------------------------------------------------------- pack Yw into MFMA B-frag order (once, from [V][F])
__global__ void pack_yw(const float* __restrict__ Yw, u16* __restrict__ Bhi, u16* __restrict__ Blo)
{
  const int q = blockIdx.x;
  const int v = blockIdx.y*256 + threadIdx.x;
  if (v >= V_) return;
  union { u16 u[32]; uint4 w[4]; } H, L;
  #pragma unroll
  for (int kk = 0; kk < 32; ++kk) {
    const int f = q*32 + kk;
    const float x = (f < F_) ? Yw[(size_t)v*F_ + f] : 0.f;
    const u16 h = bf16_rne(x);
    H.u[kk] = h;
    L.u[kk] = bf16_rne(x - bf16_to_f(h));
  }
  uint4* dh = (uint4*)(Bhi + ((size_t)q*V_ + v)*32);
  uint4* dl = (uint4*)(Blo + ((size_t)q*V_ + v)*32);
  #pragma unroll
  for (int i = 0; i < 4; ++i) { dh[i] = H.w[i]; dl[i] = L.w[i]; }
}

// ---------------------------------------------------------------- MFMA Y-GEMM + two-pass softmax partials
// 1D grid NYB=2560. XCD-pinned: all 16 b-tiles of a vb land on one XCD's L2.
// Partials: float4 {max, sumexp, argmax-bits, 0} at pm4[vb*B_ + row] (coalesced stores).
__global__ __launch_bounds__(256) void y_mfma(
    const u16* __restrict__ Ahi, const u16* __restrict__ Alo,
    const u16* __restrict__ Bhi, const u16* __restrict__ Blo,
    const float* __restrict__ Yb, float4* __restrict__ pm4)
{
  const int bid = blockIdx.x;
  const int xcd = bid & 7;
  const int i   = bid >> 3;
  const int by  = i & 15;
  const int vb  = xcd*20 + (i >> 4);     // 0..159
  if (vb >= NVB) return;
  const int v0 = vb*64;
  const int b0 = by*128;
  const int w  = threadIdx.x >> 6;
  const int l  = threadIdx.x & 63;
  const int lr = l & 15;
  const int g  = l >> 4;

  f32x4 acc[2][4] = {};

  for (int q = 0; q < KQ_; ++q) {
    bf16x8 a_h[2], a_l[2], b_h[4], b_l[4];
    #pragma unroll
    for (int mt = 0; mt < 2; ++mt) {
      const int row = b0 + w*32 + mt*16 + lr;
      const size_t off = ((size_t)(q*B_ + row))*32 + g*8;
      a_h[mt] = *(const bf16x8*)(Ahi + off);
      a_l[mt] = *(const bf16x8*)(Alo + off);
    }
    #pragma unroll
    for (int nt = 0; nt < 4; ++nt) {
      const int col = v0 + nt*16 + lr;
      if (col < V_) {
        const size_t off = ((size_t)(q*V_ + col))*32 + g*8;
        b_h[nt] = *(const bf16x8*)(Bhi + off);
        b_l[nt] = *(const bf16x8*)(Blo + off);
      } else {
        b_h[nt] = (bf16x8)0; b_l[nt] = (bf16x8)0;
      }
    }
    #pragma unroll
    for (int mt = 0; mt < 2; ++mt)
      #pragma unroll
      for (int nt = 0; nt < 4; ++nt) {
        acc[mt][nt] = __builtin_amdgcn_mfma_f32_16x16x32_bf16(a_h[mt], b_h[nt], acc[mt][nt], 0, 0, 0);
        acc[mt][nt] = __builtin_amdgcn_mfma_f32_16x16x32_bf16(a_h[mt], b_l[nt], acc[mt][nt], 0, 0, 0);
        acc[mt][nt] = __builtin_amdgcn_mfma_f32_16x16x32_bf16(a_l[mt], b_h[nt], acc[mt][nt], 0, 0, 0);
      }
  }

  // ---- pass 1: per-row max + argmax (max IS the argmax value) ----
  float ybv[4]; int vld[4];
  #pragma unroll
  for (int nt = 0; nt < 4; ++nt) {
    const int colv = v0 + nt*16 + lr;
    vld[nt] = (colv < V_);
    ybv[nt] = vld[nt] ? Yb[colv] : 0.f;
  }
  float m[2][4]; int ai[2][4];
  #pragma unroll
  for (int mt = 0; mt < 2; ++mt)
    #pragma unroll
    for (int j = 0; j < 4; ++j) { m[mt][j] = -INFINITY; ai[mt][j] = 0x7fffffff; }

  #pragma unroll
  for (int nt = 0; nt < 4; ++nt) {
    if (!vld[nt]) continue;
    const int colv = v0 + nt*16 + lr;
    #pragma unroll
    for (int mt = 0; mt < 2; ++mt)
      #pragma unroll
      for (int j = 0; j < 4; ++j) {
        const float y = acc[mt][nt][j] + ybv[nt];
        if (y > m[mt][j]) { m[mt][j] = y; ai[mt][j] = colv; }   // ascending colv -> first occurrence
      }
  }
  #pragma unroll
  for (int off = 1; off <= 8; off <<= 1) {
    #pragma unroll
    for (int mt = 0; mt < 2; ++mt)
      #pragma unroll
      for (int j = 0; j < 4; ++j) {
        const float om = __shfl_xor(m[mt][j], off);
        const int   oai = __shfl_xor(ai[mt][j], off);
        if (om > m[mt][j] || (om == m[mt][j] && oai < ai[mt][j])) { m[mt][j] = om; ai[mt][j] = oai; }
      }
  }

  // ---- pass 2: sum exp(y - rowmax) ----
  float s[2][4] = {};
  #pragma unroll
  for (int nt = 0; nt < 4; ++nt) {
    if (!vld[nt]) continue;
    #pragma unroll
    for (int mt = 0; mt < 2; ++mt)
      #pragma unroll
      for (int j = 0; j < 4; ++j)
        s[mt][j] += __expf(acc[mt][nt][j] + ybv[nt] - m[mt][j]);
  }
  #pragma unroll
  for (int off = 1; off <= 8; off <<= 1) {
    #pragma unroll
    for (int mt = 0; mt < 2; ++mt)
      #pragma unroll
      for (int j = 0; j < 4; ++j)
        s[mt][j] += __shfl_xor(s[mt][j], off);
  }

  if (lr == 0) {
    #pragma unroll
    for (int mt = 0; mt < 2; ++mt)
      #pragma unroll
      for (int j = 0; j < 4; ++j) {
        const int row = b0 + w*32 + mt*16 + g*4 + j;
        pm4[(size_t)vb*B_ + row] = make_float4(m[mt][j], s[mt][j], __int_as_float(ai[mt][j]), 0.f);
      }
  }
}

// ---------------------------------------------------------------- combine partials + exact fp32 target logit
__global__ void combine2(const float4* __restrict__ pm4,
                         const float* __restrict__ r, const float* __restrict__ Yw,
                         const float* __restrict__ Yb, const int* __restrict__ tgt,
                         int* __restrict__ w, float* __restrict__ loss_row,
                         int* __restrict__ corr_row)
{
  const int b = blockIdx.x;
  const int lane = threadIdx.x;      // 64
  const int tb = tgt[b];

  float td = 0.f;
  #pragma unroll
  for (int it = 0; it < 4; ++it) {
    const int f = lane + it*64;
    if (f < F_) td = fmaf(r[(size_t)f*B_ + b], Yw[(size_t)tb*F_ + f], td);
  }

  float M = -INFINITY, S = 0.f; int ai = 0x7fffffff;
  for (int p = lane; p < NVB; p += 64) {
    const float4 q = pm4[(size_t)p*B_ + b];
    const float mm = q.x, s = q.y;
    const int idx = __float_as_int(q.z);
    if (mm > M) ai = idx;
    else if (mm == M && idx < ai) ai = idx;
    const float M2 = fmaxf(M, mm);
    const float t1 = (M == -INFINITY) ? 0.f : S*__expf(M - M2);
    S = t1 + s*__expf(mm - M2);
    M = M2;
  }
  #pragma unroll
  for (int off = 1; off <= 32; off <<= 1) {
    td += __shfl_xor(td, off);
    const float om = __shfl_xor(M, off);
    const float os = __shfl_xor(S, off);
    const int   oai = __shfl_xor(ai, off);
    if (om > M) ai = oai;
    else if (om == M && oai < ai) ai = oai;
    const float M2 = fmaxf(M, om);
    const float t1 = (M  == -INFINITY) ? 0.f : S *__expf(M  - M2);
    const float t2 = (om == -INFINITY) ? 0.f : os*__expf(om - M2);
    S = t1 + t2;
    M = M2;
  }
  if (lane == 0) {
    const float logZ = M + logf(S);
    loss_row[b] = logZ - (td + Yb[tb]);
    corr_row[b] = (ai == tb) ? 1 : 0;
    w[b] = ai;
  }
}

// ---------------------------------------------------------------- final deterministic reduce
__global__ void finalize_k(const float* __restrict__ lr, const int* __restrict__ cr,
                           float* __restrict__ out)
{
  __shared__ float sf[256]; __shared__ int si[256];
  float s = 0.f; int c = 0;
  for (int i = threadIdx.x; i < 7*B_; i += 256) { s += lr[i]; c += cr[i]; }
  sf[threadIdx.x] = s; si[threadIdx.x] = c;
  __syncthreads();
  for (int off = 128; off; off >>= 1) {
    if (threadIdx.x < off) { sf[threadIdx.x] += sf[threadIdx.x+off]; si[threadIdx.x] += si[threadIdx.x+off]; }
    __syncthreads();
  }
  if (threadIdx.x == 0) { out[0] = sf[0] / (float)B_; out[1] = (float)si[0]; }
}

// ================================================================ host
extern "C" void kernel_launch(void* const* d_in, const int* in_sizes, int n_in,
                              void* d_out, int out_size, void* d_ws, size_t ws_size,
                              hipStream_t stream)
{
  (void)in_sizes; (void)n_in; (void)out_size; (void)ws_size;
  const int*   text = (const int*)d_in[0];
  const float* emb  = (const float*)d_in[3];
  const float* gamma= (const float*)d_in[4];
  const float* beta = (const float*)d_in[5];
  const float* c1w = (const float*)d_in[6];  const float* c1b = (const float*)d_in[7];
  const float* c2w = (const float*)d_in[8];  const float* c2b = (const float*)d_in[9];
  const float* c3w = (const float*)d_in[10]; const float* c3b = (const float*)d_in[11];
  const float* c4w = (const float*)d_in[12]; const float* c4b = (const float*)d_in[13];
  const float* Mw = (const float*)d_in[14];  const float* Mb = (const float*)d_in[15];
  const float* Uw = (const float*)d_in[16];  const float* Ub = (const float*)d_in[17];
  const float* Rw = (const float*)d_in[18];  const float* Rb = (const float*)d_in[19];
  const float* Hw = (const float*)d_in[20];  const float* Hb = (const float*)d_in[21];
  const float* Xw = (const float*)d_in[22];  const float* Xb = (const float*)d_in[23];
  const float* Yw = (const float*)d_in[24];  const float* Yb = (const float*)d_in[25];

  float* ws = (float*)d_ws;
  size_t off = 0;
  auto alloc = [&](size_t n)->float* { float* p = ws + off; off += (n + 63) & ~(size_t)63; return p; };

  float* WT_M  = alloc(400*F_);
  float* WT_U  = alloc((size_t)7*F_*F_);
  float* WT_H  = alloc((size_t)F_*F_);
  // packed weights: [NQ][256][32] u16 hi/lo
  u16* W1h = (u16*)alloc((size_t)10*256*32/2); u16* W1l = (u16*)alloc((size_t)10*256*32/2);
  u16* W2h = (u16*)alloc((size_t)13*256*32/2); u16* W2l = (u16*)alloc((size_t)13*256*32/2);
  u16* W3h = (u16*)alloc((size_t)19*256*32/2); u16* W3l = (u16*)alloc((size_t)19*256*32/2);
  u16* W4h = (u16*)alloc((size_t)19*256*32/2); u16* W4l = (u16*)alloc((size_t)19*256*32/2);
  u16* RWh = (u16*)alloc((size_t)7*256*32/2);  u16* RWl = (u16*)alloc((size_t)7*256*32/2);
  float* S1 = alloc(3*F_); float* Sh1 = alloc(3*F_);
  float* S2 = alloc(3*F_); float* Sh2 = alloc(3*F_);
  float* S3 = alloc(3*F_); float* Sh3 = alloc(3*F_);
  float* P  = alloc((size_t)NSEG_*E_*TL_*B_);     // X0 -> Y2 -> HT + packed planes
  float* Q  = alloc((size_t)NSEG_*F_*6*B_);       // Y1 -> Y3 -> Uh+US -> partials + XwT
  float* VEC = alloc((size_t)NSEG_*F_*B_);
  float* hA = alloc((size_t)F_*B_);
  float* hB = alloc((size_t)F_*B_);
  float* rA = alloc((size_t)F_*B_);
  // activation pack buffer (per z, full cols). Max: conv2: 13q*10240c*32 u16 per plane
  u16* PKh = (u16*)alloc((size_t)13*10240*32/2);
  u16* PKl = (u16*)alloc((size_t)13*10240*32/2);
  int*   wbuf = (int*)alloc(B_);
  float* loss_rows = alloc((size_t)7*B_);
  int*   corr_rows = (int*)alloc((size_t)7*B_);

  float* X0 = P;                                   // [3][150][7][B]
  float* Y1 = Q;                                   // [3][200][6][B]
  float* Y2 = P;                                   // [3][200][5][B]
  float* Y3 = Q;                                   // [3][200][3][B]
  float* Uh = Q;                                   // [7][200][B]
  float* US = Q + (size_t)7*F_*B_;                 // [7][200][B]
  float* HT = P;                                   // [7][200][B] live through scan

  const size_t HT_FL = (size_t)7*F_*B_;            // 2,867,200 floats (mult of 64)
  u16* YWhi = (u16*)(P + HT_FL);
  u16* YWlo = YWhi + (size_t)KQ_*V_*32;            // 2,240,000 u16 each
  u16* A0h  = YWlo + (size_t)KQ_*V_*32;
  u16* A0l  = A0h + (size_t)KQ_*B_*32;             // 458,752 u16 each
  u16* A1h  = A0l + (size_t)KQ_*B_*32;
  u16* A1l  = A1h + (size_t)KQ_*B_*32;
  // tail ends at P + 6,024,704 fl <= 6,451,200 OK

  float4* pm4 = (float4*)Q;                        // [NVB][B_] float4 = 1,286,144 fl
  float*  XwT = Q + (size_t)2097152;               // [V][F] = 2,000,000 fl, ends 4,097,152 <= Q size

  const dim3 tb_(32,8);
  hipLaunchKernelGGL(transpose_k, dim3(13,7,1),  tb_, 0, stream, Mw,  WT_M,  F_, 400);
  hipLaunchKernelGGL(transpose_k, dim3(7,7,7),   tb_, 0, stream, Uw,  WT_U,  F_, F_);
  hipLaunchKernelGGL(transpose_k, dim3(7,7,1),   tb_, 0, stream, Hw,  WT_H,  F_, F_);

  hipLaunchKernelGGL(pack_w, dim3(10), dim3(256), 0, stream, c1w, 300, W1h, W1l);
  hipLaunchKernelGGL(pack_w, dim3(13), dim3(256), 0, stream, c2w, 400, W2h, W2l);
  hipLaunchKernelGGL(pack_w, dim3(19), dim3(256), 0, stream, c3w, 600, W3h, W3l);
  hipLaunchKernelGGL(pack_w, dim3(19), dim3(256), 0, stream, c4w, 600, W4h, W4l);
  hipLaunchKernelGGL(pack_w, dim3(7),  dim3(256), 0, stream, Rw,  200, RWh, RWl);

  hipMemsetAsync(hA,   0, (size_t)F_*B_*4, stream);
  hipMemsetAsync(wbuf, 0, (size_t)B_*4,    stream);

  hipLaunchKernelGGL(gather_x0, dim3(B_/256, TL_, NSEG_), dim3(256), 0, stream, text, emb, X0);

  // ---- conv stack (per-z pack + streaming MFMA GEMM, full columns) ----
  for (int z = 0; z < NSEG_; ++z) {
    hipLaunchKernelGGL((pack_act<false,2>), dim3(48,10), dim3(256), 0, stream,
        X0 + (size_t)z*E_*TL_*B_, nullptr, nullptr, PKh, PKl, 300, TL_, 12288);
    hipLaunchKernelGGL((conv_gemm<false>), dim3(192), dim3(256), 0, stream,
        W1h, W1l, PKh, PKl, c1b, Y1 + (size_t)z*F_*6*B_, 10, 12288, 6);
  }
  hipLaunchKernelGGL(bn_stats, dim3(F_, NSEG_), dim3(256), 0, stream, Y1, 6, gamma, beta, S1, Sh1);
  for (int z = 0; z < NSEG_; ++z) {
    hipLaunchKernelGGL((pack_act<true,2>), dim3(40,13), dim3(256), 0, stream,
        Y1 + (size_t)z*F_*6*B_, S1 + z*F_, Sh1 + z*F_, PKh, PKl, 400, 6, 10240);
    hipLaunchKernelGGL((conv_gemm<false>), dim3(160), dim3(256), 0, stream,
        W2h, W2l, PKh, PKl, c2b, Y2 + (size_t)z*F_*5*B_, 13, 10240, 5);
  }
  hipLaunchKernelGGL(bn_stats, dim3(F_, NSEG_), dim3(256), 0, stream, Y2, 5, gamma, beta, S2, Sh2);
  for (int z = 0; z < NSEG_; ++z) {
    hipLaunchKernelGGL((pack_act<true,3>), dim3(24,19), dim3(256), 0, stream,
        Y2 + (size_t)z*F_*5*B_, S2 + z*F_, Sh2 + z*F_, PKh, PKl, 600, 5, 6144);
    hipLaunchKernelGGL((conv_gemm<false>), dim3(96), dim3(256), 0, stream,
        W3h, W3l, PKh, PKl, c3b, Y3 + (size_t)z*F_*3*B_, 19, 6144, 3);
  }
  hipLaunchKernelGGL(bn_stats, dim3(F_, NSEG_), dim3(256), 0, stream, Y3, 3, gamma, beta, S3, Sh3);
  for (int z = 0; z < NSEG_; ++z) {
    hipLaunchKernelGGL((pack_act<true,3>), dim3(8,19), dim3(256), 0, stream,
        Y3 + (size_t)z*F_*3*B_, S3 + z*F_, Sh3 + z*F_, PKh, PKl, 600, 3, 2048);
    hipLaunchKernelGGL((conv_gemm<true>), dim3(32), dim3(256), 0, stream,
        W4h, W4l, PKh, PKl, c4b, VEC + (size_t)z*F_*B_, 19, 2048, 1);
  }

  // ---- M chain (fused concat) ----
  float* hc = hA; float* hn = hB;
  for (int i = 0; i < 3; ++i) {
    hipLaunchKernelGGL((gemm_k<true,true,false,true>), dim3(4, NB64, 1), dim3(256), 0, stream,
        WT_M, 0, VEC + (size_t)i*F_*B_, 0, hc, hn, 0, Mb, 0, 400);
    float* t_ = hc; hc = hn; hn = t_;
  }

  // ---- U / us / H ----
  hipLaunchKernelGGL((gemm_k<false,true,false,false>), dim3(4, NB64, 6), dim3(256), 0, stream,
      WT_U + (size_t)F_*F_, (long long)F_*F_, hc, 0, nullptr, Uh + (size_t)F_*B_, (long long)F_*B_,
      Ub + F_, F_, 200);
  hipLaunchKernelGGL(us_build, dim3(7*F_*B_/256), dim3(256), 0, stream, Uh, US);
  hipLaunchKernelGGL((gemm_k<false,true,false,false>), dim3(4, NB64, 7), dim3(256), 0, stream,
      WT_H, 0, US, (long long)F_*B_, nullptr, HT, (long long)F_*B_, Hb, 0, 200);

  // ---- scan prep (after P-tail stops being clobbered) ----
  hipLaunchKernelGGL(transpose_k, dim3(313,7,1), tb_, 0, stream, Xw, XwT, F_, V_);
  hipLaunchKernelGGL(pack_yw, dim3(KQ_, (V_+255)/256), dim3(256), 0, stream, Yw, YWhi, YWlo);
  hipMemsetAsync(A0h, 0, (size_t)2*KQ_*B_*32*2, stream);   // zero r0 frags (A0h+A0l contiguous)

  // ---- scan ----
  u16 *cin_h = A0h, *cin_l = A0l, *cout_h = A1h, *cout_l = A1l;
  for (int t = 0; t < 7; ++t) {
    hipLaunchKernelGGL(r_step, dim3(4, 32), dim3(256), 0, stream,
        RWh, RWl, cin_h, cin_l, Rb, XwT, Xb, HT + (size_t)t*F_*B_, wbuf, rA, cout_h, cout_l);
    hipLaunchKernelGGL(y_mfma, dim3(NYB), dim3(256), 0, stream,
        cout_h, cout_l, YWhi, YWlo, Yb, pm4);
    const int* tgt_t = text + (size_t)(21 + t)*B_;
    hipLaunchKernelGGL(combine2, dim3(B_), dim3(64), 0, stream,
        pm4, rA, Yw, Yb, tgt_t, wbuf, loss_rows + (size_t)t*B_, corr_rows + (size_t)t*B_);
    u16* th = cin_h; cin_h = cout_h; cout_h = th;
    u16* tl = cin_l; cin_l = cout_l; cout_l = tl;
  }

  hipLaunchKernelGGL(finalize_k, dim3(1), dim3(256), 0, stream, loss_rows, corr_rows, (float*)d_out);
}

// Round 8
// 1367.910 us; speedup vs baseline: 1.3489x; 1.1073x over previous
//
#include <hip/hip_runtime.h>
#include <math.h>

#define V_    10000
#define E_    150
#define F_    200
#define TL_   7
#define B_    2048
#define NSEG_ 3
#define EPS_  1e-5f
#define SLOPE_ 0.01f
#define NB64  (B_/64)
#define NVB   157          // ceil(10000/64) v-parts for MFMA Y-GEMM
#define NYB   2560         // 8 xcd * 20 vb-slots * 16 b-tiles
#define KQ_   7            // K chunks of 32 for F_=200 (padded 224)

typedef unsigned short u16;
typedef __attribute__((ext_vector_type(8))) short bf16x8;
typedef __attribute__((ext_vector_type(4))) float f32x4;

__device__ __forceinline__ float leaky_f(float x){ return x >= 0.f ? x : SLOPE_*x; }
__device__ __forceinline__ u16 bf16_rne(float x){
  unsigned u = __float_as_uint(x);
  unsigned r = (u + 0x7FFFu + ((u>>16)&1u)) >> 16;
  return (u16)r;
}
__device__ __forceinline__ float bf16_to_f(u16 h){ return __uint_as_float(((unsigned)h)<<16); }

// ---------------------------------------------------------------- transpose (used for XwT only)
__global__ void transpose_k(const float* __restrict__ in, float* __restrict__ out,
                            int R, int C)
{
  __shared__ float tile[32][33];
  const long long bofs = (long long)blockIdx.z * R * C;
  in += bofs; out += bofs;
  const int c0 = blockIdx.x*32, r0 = blockIdx.y*32;
  const int tx = threadIdx.x, ty = threadIdx.y;  // (32,8)
  for (int i = ty; i < 32; i += 8) {
    int r = r0 + i, c = c0 + tx;
    if (r < R && c < C) tile[i][tx] = in[(long long)r*C + c];
  }
  __syncthreads();
  for (int i = ty; i < 32; i += 8) {
    int c = c0 + i, r = r0 + tx;
    if (c < C && r < R) out[(long long)c*R + r] = tile[tx][i];
  }
}

// ---------------------------------------------------------------- embedding gather
__global__ void gather_x0(const int* __restrict__ text, const float* __restrict__ emb,
                          float* __restrict__ X0)
{
  const int b = blockIdx.x*256 + threadIdx.x;
  const int l = blockIdx.y, j = blockIdx.z;
  const int s = j*TL_ + l;
  const int row = text[(long long)s*B_ + b];
  const float* er = emb + (long long)row*E_;
  float* xp = X0 + ((long long)j*E_*TL_ + l)*B_ + b;
  for (int e = 0; e < E_; ++e) xp[(long long)e*TL_*B_] = er[e];
}

// ---------------------------------------------------------------- weight pack
// W [F][Kstride] (cols [0,Keff) used) -> frag [q][256][32] hi/lo; z-batched.
__global__ void pack_w(const float* __restrict__ W, int Kstride, int Keff, long long wZi,
                       u16* __restrict__ Wh, u16* __restrict__ Wl, long long wZo)
{
  const int q = blockIdx.x;
  const int z = blockIdx.y;
  const int f = threadIdx.x;        // 256
  W  += (size_t)z*wZi;
  Wh += (size_t)z*wZo; Wl += (size_t)z*wZo;
  union { u16 u[32]; uint4 v[4]; } H, L;
  #pragma unroll
  for (int kk = 0; kk < 32; ++kk) {
    const int k = q*32 + kk;
    const float x = (k < Keff && f < F_) ? W[(size_t)f*Kstride + k] : 0.f;
    const u16 h = bf16_rne(x);
    H.u[kk] = h;
    L.u[kk] = bf16_rne(x - bf16_to_f(h));
  }
  uint4* dh = (uint4*)(Wh + ((size_t)q*256 + f)*32);
  uint4* dl = (uint4*)(Wl + ((size_t)q*256 + f)*32);
  #pragma unroll
  for (int i = 0; i < 4; ++i) { dh[i] = H.v[i]; dl[i] = L.v[i]; }
}

// ---------------------------------------------------------------- pack fp32 [z][F][B] -> frags [z][q][B][32]
__global__ void pack_x(const float* __restrict__ X, long long xZ,
                       u16* __restrict__ Oh, u16* __restrict__ Ol, long long oZ)
{
  const int q = blockIdx.y, z = blockIdx.z;
  const int b = blockIdx.x*256 + threadIdx.x;
  X  += (size_t)z*xZ;
  Oh += (size_t)z*oZ; Ol += (size_t)z*oZ;
  union { u16 u[32]; uint4 v[4]; } H, L;
  #pragma unroll
  for (int kk = 0; kk < 32; ++kk) {
    const int k = q*32 + kk;
    const float x = (k < F_) ? X[(size_t)k*B_ + b] : 0.f;
    const u16 h = bf16_rne(x);
    H.u[kk] = h;
    L.u[kk] = bf16_rne(x - bf16_to_f(h));
  }
  uint4* dh = (uint4*)(Oh + ((size_t)q*B_ + b)*32);
  uint4* dl = (uint4*)(Ol + ((size_t)q*B_ + b)*32);
  #pragma unroll
  for (int i = 0; i < 4; ++i) { dh[i] = H.v[i]; dl[i] = L.v[i]; }
}

// ---------------------------------------------------------------- generic MFMA GEMM (r_step structure)
// C[z] = act(W1[z] @ X1[z] (+ W2 @ X2) + bias[z]); output fp32 and/or packed frags.
// W2/X2 only used with gridDim.z == 1.
template<bool TWO, bool LEAKY, bool OUT_F32, bool OUT_PK>
__global__ __launch_bounds__(256) void mf_gemm(
    const u16* __restrict__ W1h, const u16* __restrict__ W1l, long long wZ,
    const u16* __restrict__ X1h, const u16* __restrict__ X1l, long long xZ,
    const u16* __restrict__ W2h, const u16* __restrict__ W2l,
    const u16* __restrict__ X2h, const u16* __restrict__ X2l,
    const float* __restrict__ bias, long long bZ,
    float* __restrict__ Cf, long long cZ,
    u16* __restrict__ Oh, u16* __restrict__ Ol)
{
  const int z = blockIdx.z;
  W1h += (size_t)z*wZ; W1l += (size_t)z*wZ;
  X1h += (size_t)z*xZ; X1l += (size_t)z*xZ;
  const float* bz = bias + (size_t)z*bZ;
  if (OUT_F32) Cf += (size_t)z*cZ;

  const int f0 = blockIdx.x*64;
  const int b0 = blockIdx.y*64;
  const int tid = threadIdx.x;
  const int w = tid >> 6, l = tid & 63;
  const int lr = l & 15, g = l >> 4;

  __shared__ float T[64][65];

  f32x4 acc[4] = {};
  for (int q = 0; q < KQ_; ++q) {
    {
      const size_t aoff = ((size_t)q*256 + (f0 + w*16 + lr))*32 + g*8;
      const bf16x8 ah = *(const bf16x8*)(W1h + aoff);
      const bf16x8 al = *(const bf16x8*)(W1l + aoff);
      #pragma unroll
      for (int nt = 0; nt < 4; ++nt) {
        const size_t boff = ((size_t)q*B_ + (b0 + nt*16 + lr))*32 + g*8;
        const bf16x8 bh = *(const bf16x8*)(X1h + boff);
        const bf16x8 bl = *(const bf16x8*)(X1l + boff);
        acc[nt] = __builtin_amdgcn_mfma_f32_16x16x32_bf16(ah, bh, acc[nt], 0, 0, 0);
        acc[nt] = __builtin_amdgcn_mfma_f32_16x16x32_bf16(ah, bl, acc[nt], 0, 0, 0);
        acc[nt] = __builtin_amdgcn_mfma_f32_16x16x32_bf16(al, bh, acc[nt], 0, 0, 0);
      }
    }
    if (TWO) {
      const size_t aoff = ((size_t)q*256 + (f0 + w*16 + lr))*32 + g*8;
      const bf16x8 ah = *(const bf16x8*)(W2h + aoff);
      const bf16x8 al = *(const bf16x8*)(W2l + aoff);
      #pragma unroll
      for (int nt = 0; nt < 4; ++nt) {
        const size_t boff = ((size_t)q*B_ + (b0 + nt*16 + lr))*32 + g*8;
        const bf16x8 bh = *(const bf16x8*)(X2h + boff);
        const bf16x8 bl = *(const bf16x8*)(X2l + boff);
        acc[nt] = __builtin_amdgcn_mfma_f32_16x16x32_bf16(ah, bh, acc[nt], 0, 0, 0);
        acc[nt] = __builtin_amdgcn_mfma_f32_16x16x32_bf16(ah, bl, acc[nt], 0, 0, 0);
        acc[nt] = __builtin_amdgcn_mfma_f32_16x16x32_bf16(al, bh, acc[nt], 0, 0, 0);
      }
    }
  }
  #pragma unroll
  for (int nt = 0; nt < 4; ++nt)
    #pragma unroll
    for (int j = 0; j < 4; ++j)
      T[w*16 + g*4 + j][nt*16 + lr] = acc[nt][j];
  __syncthreads();

  const int ty = tid >> 4, tx = tid & 15;
  #pragma unroll
  for (int i = 0; i < 4; ++i) {
    const int f = f0 + ty*4 + i;
    if (f < F_) {
      const float bb = bz[f];
      #pragma unroll
      for (int j = 0; j < 4; ++j) {
        float v = T[ty*4 + i][tx*4 + j] + bb;
        if (LEAKY) v = leaky_f(v);
        if (OUT_F32) Cf[(size_t)f*B_ + b0 + tx*4 + j] = v;
        T[ty*4 + i][tx*4 + j] = v;
      }
    } else {
      #pragma unroll
      for (int j = 0; j < 4; ++j) T[ty*4 + i][tx*4 + j] = 0.f;
    }
  }
  __syncthreads();

  if (OUT_PK) {
    const int bcol = tid & 63;
    const int kk0 = (tid >> 6)*8;
    #pragma unroll
    for (int qh = 0; qh < 2; ++qh) {
      const int q = (f0 >> 5) + qh;
      if (q >= KQ_) continue;
      union { u16 u[8]; uint4 v2[1]; } H, L;
      #pragma unroll
      for (int u = 0; u < 8; ++u) {
        const float x = T[qh*32 + kk0 + u][bcol];
        const u16 h = bf16_rne(x);
        H.u[u] = h;
        L.u[u] = bf16_rne(x - bf16_to_f(h));
      }
      const size_t off = ((size_t)q*B_ + b0 + bcol)*32 + kk0;
      *(uint4*)(Oh + off) = H.v2[0];
      *(uint4*)(Ol + off) = L.v2[0];
    }
  }
}

// ---------------------------------------------------------------- activation pack (BN+leaky fused), per z (conv)
template<bool BN, int KW>
__global__ void pack_act(const float* __restrict__ Y,
                         const float* __restrict__ bnS, const float* __restrict__ bnH,
                         u16* __restrict__ Ph, u16* __restrict__ Pl,
                         int K, int Lin, int Ncols)
{
  const int q = blockIdx.y;
  const int c = blockIdx.x*256 + threadIdx.x;
  const int t = c >> 11, b = c & 2047;
  union { u16 u[32]; uint4 v[4]; } H, L;
  #pragma unroll
  for (int kk = 0; kk < 32; ++kk) {
    const int k = q*32 + kk;
    float x = 0.f;
    if (k < K) {
      const int e = k / KW, kw = k - e*KW;
      x = Y[((size_t)e*Lin + (t + kw))*B_ + b];
      if (BN) { x = fmaf(x, bnS[e], bnH[e]); x = leaky_f(x); }
    }
    const u16 h = bf16_rne(x);
    H.u[kk] = h;
    L.u[kk] = bf16_rne(x - bf16_to_f(h));
  }
  uint4* dh = (uint4*)(Ph + ((size_t)q*Ncols + c)*32);
  uint4* dl = (uint4*)(Pl + ((size_t)q*Ncols + c)*32);
  #pragma unroll
  for (int i = 0; i < 4; ++i) { dh[i] = H.v[i]; dl[i] = L.v[i]; }
}

// ---------------------------------------------------------------- conv GEMM: pure streaming MFMA, per z
template<bool OUT_LEAKY>
__global__ __launch_bounds__(256) void conv_gemm(
    const u16* __restrict__ Wh, const u16* __restrict__ Wl,
    const u16* __restrict__ Ph, const u16* __restrict__ Pl,
    const float* __restrict__ bias, float* __restrict__ C,
    int NQ, int Ncols, int Lout)
{
  const int c0 = blockIdx.x*64;
  const int w  = threadIdx.x >> 6;
  const int l  = threadIdx.x & 63;
  const int lr = l & 15, g = l >> 4;

  f32x4 acc[4][4] = {};

  for (int q = 0; q < NQ; ++q) {
    bf16x8 bh[4], bl[4];
    #pragma unroll
    for (int nt = 0; nt < 4; ++nt) {
      const size_t off = ((size_t)q*Ncols + (c0 + nt*16 + lr))*32 + g*8;
      bh[nt] = *(const bf16x8*)(Ph + off);
      bl[nt] = *(const bf16x8*)(Pl + off);
    }
    #pragma unroll
    for (int mt = 0; mt < 4; ++mt) {
      const size_t woff = ((size_t)q*256 + (w*64 + mt*16 + lr))*32 + g*8;
      const bf16x8 ah = *(const bf16x8*)(Wh + woff);
      const bf16x8 al = *(const bf16x8*)(Wl + woff);
      #pragma unroll
      for (int nt = 0; nt < 4; ++nt) {
        acc[mt][nt] = __builtin_amdgcn_mfma_f32_16x16x32_bf16(ah, bh[nt], acc[mt][nt], 0, 0, 0);
        acc[mt][nt] = __builtin_amdgcn_mfma_f32_16x16x32_bf16(ah, bl[nt], acc[mt][nt], 0, 0, 0);
        acc[mt][nt] = __builtin_amdgcn_mfma_f32_16x16x32_bf16(al, bh[nt], acc[mt][nt], 0, 0, 0);
      }
    }
  }

  #pragma unroll
  for (int mt = 0; mt < 4; ++mt)
    #pragma unroll
    for (int j = 0; j < 4; ++j) {
      const int f = w*64 + mt*16 + g*4 + j;
      if (f < F_) {
        const float bs = bias[f];
        #pragma unroll
        for (int nt = 0; nt < 4; ++nt) {
          const int col = c0 + nt*16 + lr;
          const int t = col >> 11, b = col & 2047;
          float v = acc[mt][nt][j] + bs;
          if (OUT_LEAKY) v = leaky_f(v);
          C[((size_t)f*Lout + t)*B_ + b] = v;
        }
      }
    }
}

// ---------------------------------------------------------------- BN stats
__global__ void bn_stats(const float* __restrict__ Y, int L,
                         const float* __restrict__ gamma, const float* __restrict__ beta,
                         float* __restrict__ scale, float* __restrict__ shift)
{
  const int f = blockIdx.x, j = blockIdx.y;
  const float* p = Y + ((long long)(j*F_ + f))*L*B_;
  const int N = L*B_;
  double s = 0.0, s2 = 0.0;
  for (int i = threadIdx.x; i < N; i += 256) { double x = p[i]; s += x; s2 += x*x; }
  __shared__ double sh1[256], sh2[256];
  sh1[threadIdx.x] = s; sh2[threadIdx.x] = s2;
  __syncthreads();
  for (int off = 128; off; off >>= 1) {
    if (threadIdx.x < off) { sh1[threadIdx.x] += sh1[threadIdx.x+off]; sh2[threadIdx.x] += sh2[threadIdx.x+off]; }
    __syncthreads();
  }
  if (threadIdx.x == 0) {
    const double mean = sh1[0]/N;
    const double var  = sh2[0]/N - mean*mean;
    const float rstd = rsqrtf((float)var + EPS_);
    const float sc = gamma[f]*rstd;
    scale[j*F_+f] = sc;
    shift[j*F_+f] = beta[f] - (float)mean*sc;
  }
}

// ---------------------------------------------------------------- u_steps build
__global__ void us_build(const float* __restrict__ Uh, float* __restrict__ US)
{
  const long long i = (long long)blockIdx.x*256 + threadIdx.x;
  const long long FB = (long long)F_*B_;
  const int t = (int)(i / FB);
  const long long rem = i % FB;
  const int src = (t == 0) ? 6 : t;
  const float v = Uh[(long long)src*FB + rem];
  US[i] = (t < 5) ? leaky_f(v) : v;
}

// ---------------------------------------------------------------- fused scan step (MFMA): r-GEMM + finish + repack
__global__ __launch_bounds__(256) void r_step(
    const u16* __restrict__ RWh, const u16* __restrict__ RWl,
    const u16* __restrict__ Ain_h, const u16* __restrict__ Ain_l,
    const float* __restrict__ Rb, const float* __restrict__ XwT,
    const float* __restrict__ Xb, const float* __restrict__ HTt,
    const int* __restrict__ wprev,
    float* __restrict__ rn, u16* __restrict__ Ahi, u16* __restrict__ Alo)
{
  const int f0 = blockIdx.x*64;
  const int b0 = blockIdx.y*64;
  const int tid = threadIdx.x;
  const int w = tid >> 6, l = tid & 63;
  const int lr = l & 15, g = l >> 4;

  __shared__ float T[64][65];

  f32x4 acc[4] = {};
  for (int q = 0; q < KQ_; ++q) {
    const size_t aoff = ((size_t)q*256 + (f0 + w*16 + lr))*32 + g*8;
    const bf16x8 ah = *(const bf16x8*)(RWh + aoff);
    const bf16x8 al = *(const bf16x8*)(RWl + aoff);
    #pragma unroll
    for (int nt = 0; nt < 4; ++nt) {
      const size_t boff = ((size_t)q*B_ + (b0 + nt*16 + lr))*32 + g*8;
      const bf16x8 bh = *(const bf16x8*)(Ain_h + boff);
      const bf16x8 bl = *(const bf16x8*)(Ain_l + boff);
      acc[nt] = __builtin_amdgcn_mfma_f32_16x16x32_bf16(ah, bh, acc[nt], 0, 0, 0);
      acc[nt] = __builtin_amdgcn_mfma_f32_16x16x32_bf16(ah, bl, acc[nt], 0, 0, 0);
      acc[nt] = __builtin_amdgcn_mfma_f32_16x16x32_bf16(al, bh, acc[nt], 0, 0, 0);
    }
  }
  #pragma unroll
  for (int nt = 0; nt < 4; ++nt)
    #pragma unroll
    for (int j = 0; j < 4; ++j)
      T[w*16 + g*4 + j][nt*16 + lr] = acc[nt][j];
  __syncthreads();

  const int ty = tid >> 4, tx = tid & 15;
  int wv[4];
  #pragma unroll
  for (int j = 0; j < 4; ++j) {
    int t_ = wprev[b0 + tx*4 + j];
    wv[j] = (t_ < 0) ? 0 : (t_ >= V_ ? V_-1 : t_);
  }

  #pragma unroll
  for (int i = 0; i < 4; ++i) {
    const int f = f0 + ty*4 + i;
    if (f < F_) {
      const float rb = Rb[f] + Xb[f];
      #pragma unroll
      for (int j = 0; j < 4; ++j) {
        const int b = b0 + tx*4 + j;
        float v = T[ty*4 + i][tx*4 + j] + rb + XwT[(size_t)wv[j]*F_ + f] + HTt[(size_t)f*B_ + b];
        v = leaky_f(v);
        rn[(size_t)f*B_ + b] = v;
        T[ty*4 + i][tx*4 + j] = v;
      }
    } else {
      #pragma unroll
      for (int j = 0; j < 4; ++j) T[ty*4 + i][tx*4 + j] = 0.f;
    }
  }
  __syncthreads();

  const int bcol = tid & 63;
  const int kk0 = (tid >> 6)*8;
  #pragma unroll
  for (int qh = 0; qh < 2; ++qh) {
    const int q = (f0 >> 5) + qh;
    if (q >= KQ_) continue;
    union { u16 u[8]; uint4 v2[1]; } H, L;
    #pragma unroll
    for (int u = 0; u < 8; ++u) {
      const float x = T[qh*32 + kk0 + u][bcol];
      const u16 h = bf16_rne(x);
      H.u[u] = h;
      L.u[u] = bf16_rne(x - bf16_to_f(h));
    }
    const size_t off = ((size_t)q*B_ + b0 + bcol)*32 + kk0;
    *(uint4*)(Ahi + off) = H.v2[0];
    *(uint4*)(Alo + off) = L.v2[0];
  }
}

// ---------------------------------------------------------------- pack Yw into MFMA B-frag order (once, from [V][F])
__global__ void pack_yw(const float* __restrict__ Yw, u16* __restrict__ Bhi, u16* __restrict__ Blo)
{
  const int q = blockIdx.x;
  const int v = blockIdx.y*256 + threadIdx.x;
  if (v >= V_) return;
  union { u16 u[32]; uint4 w[4]; } H, L;
  #pragma unroll
  for (int kk = 0; kk < 32; ++kk) {
    const int f = q*32 + kk;
    const float x = (f < F_) ? Yw[(size_t)v*F_ + f] : 0.f;
    const u16 h = bf16_rne(x);
    H.u[kk] = h;
    L.u[kk] = bf16_rne(x - bf16_to_f(h));
  }
  uint4* dh = (uint4*)(Bhi + ((size_t)q*V_ + v)*32);
  uint4* dl = (uint4*)(Blo + ((size_t)q*V_ + v)*32);
  #pragma unroll
  for (int i = 0; i < 4; ++i) { dh[i] = H.w[i]; dl[i] = L.w[i]; }
}

// ---------------------------------------------------------------- MFMA Y-GEMM + two-pass softmax partials
__global__ __launch_bounds__(256) void y_mfma(
    const u16* __restrict__ Ahi, const u16* __restrict__ Alo,
    const u16* __restrict__ Bhi, const u16* __restrict__ Blo,
    const float* __restrict__ Yb, float4* __restrict__ pm4)
{
  const int bid = blockIdx.x;
  const int xcd = bid & 7;
  const int i   = bid >> 3;
  const int by  = i & 15;
  const int vb  = xcd*20 + (i >> 4);     // 0..159
  if (vb >= NVB) return;
  const int v0 = vb*64;
  const int b0 = by*128;
  const int w  = threadIdx.x >> 6;
  const int l  = threadIdx.x & 63;
  const int lr = l & 15;
  const int g  = l >> 4;

  f32x4 acc[2][4] = {};

  for (int q = 0; q < KQ_; ++q) {
    bf16x8 a_h[2], a_l[2], b_h[4], b_l[4];
    #pragma unroll
    for (int mt = 0; mt < 2; ++mt) {
      const int row = b0 + w*32 + mt*16 + lr;
      const size_t off = ((size_t)(q*B_ + row))*32 + g*8;
      a_h[mt] = *(const bf16x8*)(Ahi + off);
      a_l[mt] = *(const bf16x8*)(Alo + off);
    }
    #pragma unroll
    for (int nt = 0; nt < 4; ++nt) {
      const int col = v0 + nt*16 + lr;
      if (col < V_) {
        const size_t off = ((size_t)(q*V_ + col))*32 + g*8;
        b_h[nt] = *(const bf16x8*)(Bhi + off);
        b_l[nt] = *(const bf16x8*)(Blo + off);
      } else {
        b_h[nt] = (bf16x8)0; b_l[nt] = (bf16x8)0;
      }
    }
    #pragma unroll
    for (int mt = 0; mt < 2; ++mt)
      #pragma unroll
      for (int nt = 0; nt < 4; ++nt) {
        acc[mt][nt] = __builtin_amdgcn_mfma_f32_16x16x32_bf16(a_h[mt], b_h[nt], acc[mt][nt], 0, 0, 0);
        acc[mt][nt] = __builtin_amdgcn_mfma_f32_16x16x32_bf16(a_h[mt], b_l[nt], acc[mt][nt], 0, 0, 0);
        acc[mt][nt] = __builtin_amdgcn_mfma_f32_16x16x32_bf16(a_l[mt], b_h[nt], acc[mt][nt], 0, 0, 0);
      }
  }

  float ybv[4]; int vld[4];
  #pragma unroll
  for (int nt = 0; nt < 4; ++nt) {
    const int colv = v0 + nt*16 + lr;
    vld[nt] = (colv < V_);
    ybv[nt] = vld[nt] ? Yb[colv] : 0.f;
  }
  float m[2][4]; int ai[2][4];
  #pragma unroll
  for (int mt = 0; mt < 2; ++mt)
    #pragma unroll
    for (int j = 0; j < 4; ++j) { m[mt][j] = -INFINITY; ai[mt][j] = 0x7fffffff; }

  #pragma unroll
  for (int nt = 0; nt < 4; ++nt) {
    if (!vld[nt]) continue;
    const int colv = v0 + nt*16 + lr;
    #pragma unroll
    for (int mt = 0; mt < 2; ++mt)
      #pragma unroll
      for (int j = 0; j < 4; ++j) {
        const float y = acc[mt][nt][j] + ybv[nt];
        if (y > m[mt][j]) { m[mt][j] = y; ai[mt][j] = colv; }
      }
  }
  #pragma unroll
  for (int off = 1; off <= 8; off <<= 1) {
    #pragma unroll
    for (int mt = 0; mt < 2; ++mt)
      #pragma unroll
      for (int j = 0; j < 4; ++j) {
        const float om = __shfl_xor(m[mt][j], off);
        const int   oai = __shfl_xor(ai[mt][j], off);
        if (om > m[mt][j] || (om == m[mt][j] && oai < ai[mt][j])) { m[mt][j] = om; ai[mt][j] = oai; }
      }
  }

  float s[2][4] = {};
  #pragma unroll
  for (int nt = 0; nt < 4; ++nt) {
    if (!vld[nt]) continue;
    #pragma unroll
    for (int mt = 0; mt < 2; ++mt)
      #pragma unroll
      for (int j = 0; j < 4; ++j)
        s[mt][j] += __expf(acc[mt][nt][j] + ybv[nt] - m[mt][j]);
  }
  #pragma unroll
  for (int off = 1; off <= 8; off <<= 1) {
    #pragma unroll
    for (int mt = 0; mt < 2; ++mt)
      #pragma unroll
      for (int j = 0; j < 4; ++j)
        s[mt][j] += __shfl_xor(s[mt][j], off);
  }

  if (lr == 0) {
    #pragma unroll
    for (int mt = 0; mt < 2; ++mt)
      #pragma unroll
      for (int j = 0; j < 4; ++j) {
        const int row = b0 + w*32 + mt*16 + g*4 + j;
        pm4[(size_t)vb*B_ + row] = make_float4(m[mt][j], s[mt][j], __int_as_float(ai[mt][j]), 0.f);
      }
  }
}

// ---------------------------------------------------------------- combine partials + exact fp32 target logit
__global__ void combine2(const float4* __restrict__ pm4,
                         const float* __restrict__ r, const float* __restrict__ Yw,
                         const float* __restrict__ Yb, const int* __restrict__ tgt,
                         int* __restrict__ w, float* __restrict__ loss_row,
                         int* __restrict__ corr_row)
{
  const int b = blockIdx.x;
  const int lane = threadIdx.x;      // 64
  const int tb = tgt[b];

  float td = 0.f;
  #pragma unroll
  for (int it = 0; it < 4; ++it) {
    const int f = lane + it*64;
    if (f < F_) td = fmaf(r[(size_t)f*B_ + b], Yw[(size_t)tb*F_ + f], td);
  }

  float M = -INFINITY, S = 0.f; int ai = 0x7fffffff;
  for (int p = lane; p < NVB; p += 64) {
    const float4 q = pm4[(size_t)p*B_ + b];
    const float mm = q.x, s = q.y;
    const int idx = __float_as_int(q.z);
    if (mm > M) ai = idx;
    else if (mm == M && idx < ai) ai = idx;
    const float M2 = fmaxf(M, mm);
    const float t1 = (M == -INFINITY) ? 0.f : S*__expf(M - M2);
    S = t1 + s*__expf(mm - M2);
    M = M2;
  }
  #pragma unroll
  for (int off = 1; off <= 32; off <<= 1) {
    td += __shfl_xor(td, off);
    const float om = __shfl_xor(M, off);
    const float os = __shfl_xor(S, off);
    const int   oai = __shfl_xor(ai, off);
    if (om > M) ai = oai;
    else if (om == M && oai < ai) ai = oai;
    const float M2 = fmaxf(M, om);
    const float t1 = (M  == -INFINITY) ? 0.f : S *__expf(M  - M2);
    const float t2 = (om == -INFINITY) ? 0.f : os*__expf(om - M2);
    S = t1 + t2;
    M = M2;
  }
  if (lane == 0) {
    const float logZ = M + logf(S);
    loss_row[b] = logZ - (td + Yb[tb]);
    corr_row[b] = (ai == tb) ? 1 : 0;
    w[b] = ai;
  }
}

// ---------------------------------------------------------------- final deterministic reduce
__global__ void finalize_k(const float* __restrict__ lr, const int* __restrict__ cr,
                           float* __restrict__ out)
{
  __shared__ float sf[256]; __shared__ int si[256];
  float s = 0.f; int c = 0;
  for (int i = threadIdx.x; i < 7*B_; i += 256) { s += lr[i]; c += cr[i]; }
  sf[threadIdx.x] = s; si[threadIdx.x] = c;
  __syncthreads();
  for (int off = 128; off; off >>= 1) {
    if (threadIdx.x < off) { sf[threadIdx.x] += sf[threadIdx.x+off]; si[threadIdx.x] += si[threadIdx.x+off]; }
    __syncthreads();
  }
  if (threadIdx.x == 0) { out[0] = sf[0] / (float)B_; out[1] = (float)si[0]; }
}

// ================================================================ host
extern "C" void kernel_launch(void* const* d_in, const int* in_sizes, int n_in,
                              void* d_out, int out_size, void* d_ws, size_t ws_size,
                              hipStream_t stream)
{
  (void)in_sizes; (void)n_in; (void)out_size; (void)ws_size;
  const int*   text = (const int*)d_in[0];
  const float* emb  = (const float*)d_in[3];
  const float* gamma= (const float*)d_in[4];
  const float* beta = (const float*)d_in[5];
  const float* c1w = (const float*)d_in[6];  const float* c1b = (const float*)d_in[7];
  const float* c2w = (const float*)d_in[8];  const float* c2b = (const float*)d_in[9];
  const float* c3w = (const float*)d_in[10]; const float* c3b = (const float*)d_in[11];
  const float* c4w = (const float*)d_in[12]; const float* c4b = (const float*)d_in[13];
  const float* Mw = (const float*)d_in[14];  const float* Mb = (const float*)d_in[15];
  const float* Uw = (const float*)d_in[16];  const float* Ub = (const float*)d_in[17];
  const float* Rw = (const float*)d_in[18];  const float* Rb = (const float*)d_in[19];
  const float* Hw = (const float*)d_in[20];  const float* Hb = (const float*)d_in[21];
  const float* Xw = (const float*)d_in[22];  const float* Xb = (const float*)d_in[23];
  const float* Yw = (const float*)d_in[24];  const float* Yb = (const float*)d_in[25];

  float* ws = (float*)d_ws;
  size_t off = 0;
  auto alloc = [&](size_t n)->float* { float* p = ws + off; off += (n + 63) & ~(size_t)63; return p; };

  // packed weights: [NQ][256][32] u16 hi/lo
  u16* W1h = (u16*)alloc((size_t)10*256*32/2); u16* W1l = (u16*)alloc((size_t)10*256*32/2);
  u16* W2h = (u16*)alloc((size_t)13*256*32/2); u16* W2l = (u16*)alloc((size_t)13*256*32/2);
  u16* W3h = (u16*)alloc((size_t)19*256*32/2); u16* W3l = (u16*)alloc((size_t)19*256*32/2);
  u16* W4h = (u16*)alloc((size_t)19*256*32/2); u16* W4l = (u16*)alloc((size_t)19*256*32/2);
  u16* RWh = (u16*)alloc((size_t)7*256*32/2);  u16* RWl = (u16*)alloc((size_t)7*256*32/2);
  u16* MW1h= (u16*)alloc((size_t)7*256*32/2);  u16* MW1l= (u16*)alloc((size_t)7*256*32/2);
  u16* MW2h= (u16*)alloc((size_t)7*256*32/2);  u16* MW2l= (u16*)alloc((size_t)7*256*32/2);
  u16* UWh = (u16*)alloc((size_t)6*7*256*32/2);u16* UWl = (u16*)alloc((size_t)6*7*256*32/2);
  u16* HWh = (u16*)alloc((size_t)7*256*32/2);  u16* HWl = (u16*)alloc((size_t)7*256*32/2);
  float* S1 = alloc(3*F_); float* Sh1 = alloc(3*F_);
  float* S2 = alloc(3*F_); float* Sh2 = alloc(3*F_);
  float* S3 = alloc(3*F_); float* Sh3 = alloc(3*F_);
  float* P  = alloc((size_t)NSEG_*E_*TL_*B_);     // X0 -> Y2 -> HT + packed planes
  float* Q  = alloc((size_t)NSEG_*F_*6*B_);       // Y1 -> Y3 -> Uh+US+hpk -> pm4+XwT
  float* VEC = alloc((size_t)NSEG_*F_*B_);
  float* rA = alloc((size_t)F_*B_);
  // conv activation pack buffer; later reused for vecpk then uspk
  u16* PKh = (u16*)alloc((size_t)13*10240*32/2);
  u16* PKl = (u16*)alloc((size_t)13*10240*32/2);
  int*   wbuf = (int*)alloc(B_);
  float* loss_rows = alloc((size_t)7*B_);
  int*   corr_rows = (int*)alloc((size_t)7*B_);

  float* X0 = P;                                   // [3][150][7][B]
  float* Y1 = Q;                                   // [3][200][6][B]
  float* Y2 = P;                                   // [3][200][5][B]
  float* Y3 = Q;                                   // [3][200][3][B]
  float* Uh = Q;                                   // [7][200][B]
  float* US = Q + (size_t)7*F_*B_;                 // [7][200][B]
  float* HT = P;                                   // [7][200][B] live through scan

  const size_t HT_FL = (size_t)7*F_*B_;            // 2,867,200 floats
  u16* YWhi = (u16*)(P + HT_FL);
  u16* YWlo = YWhi + (size_t)KQ_*V_*32;            // 2,240,000 u16 each
  u16* A0h  = YWlo + (size_t)KQ_*V_*32;
  u16* A0l  = A0h + (size_t)KQ_*B_*32;             // 458,752 u16 each
  u16* A1h  = A0l + (size_t)KQ_*B_*32;
  u16* A1l  = A1h + (size_t)KQ_*B_*32;
  // tail ends at P + 6,024,704 fl <= 6,451,200 OK

  // h fragment double-buffer in Q tail (after US region: 5,734,400)
  u16* hAh = (u16*)(Q + (size_t)5734400);
  u16* hAl = hAh + (size_t)KQ_*B_*32;
  u16* hBh = hAl + (size_t)KQ_*B_*32;
  u16* hBl = hBh + (size_t)KQ_*B_*32;              // ends Q + 6,651,904 fl <= 7,372,800 OK

  // vecpk / uspk overlay the (dead) conv pack buffers
  u16* VPh = PKh;  u16* VPl = PKl;                 // [3][7][B][32] = 1,376,256 u16 <= 21,299,200 bytes OK
  u16* USh = PKh;  u16* USl = PKl;                 // [7][7][B][32] = 3,211,264 u16 OK

  float4* pm4 = (float4*)Q;                        // scan: [NVB][B_] float4
  float*  XwT = Q + (size_t)2097152;               // scan: [V][F]

  const long long FRZ = (long long)KQ_*B_*32;      // frag z-stride (u16 elems)
  const long long WQZ = (long long)KQ_*256*32;     // packed-weight z-stride

  const dim3 tb_(32,8);
  // weight packs
  hipLaunchKernelGGL(pack_w, dim3(10,1), dim3(256), 0, stream, c1w, 300, 300, 0, W1h, W1l, 0);
  hipLaunchKernelGGL(pack_w, dim3(13,1), dim3(256), 0, stream, c2w, 400, 400, 0, W2h, W2l, 0);
  hipLaunchKernelGGL(pack_w, dim3(19,1), dim3(256), 0, stream, c3w, 600, 600, 0, W3h, W3l, 0);
  hipLaunchKernelGGL(pack_w, dim3(19,1), dim3(256), 0, stream, c4w, 600, 600, 0, W4h, W4l, 0);
  hipLaunchKernelGGL(pack_w, dim3(7,1),  dim3(256), 0, stream, Rw,  200, 200, 0, RWh, RWl, 0);
  hipLaunchKernelGGL(pack_w, dim3(7,1),  dim3(256), 0, stream, Mw,       400, 200, 0, MW1h, MW1l, 0);
  hipLaunchKernelGGL(pack_w, dim3(7,1),  dim3(256), 0, stream, Mw + 200, 400, 200, 0, MW2h, MW2l, 0);
  hipLaunchKernelGGL(pack_w, dim3(7,6),  dim3(256), 0, stream, Uw + (size_t)F_*F_, 200, 200, (long long)F_*F_, UWh, UWl, WQZ);
  hipLaunchKernelGGL(pack_w, dim3(7,1),  dim3(256), 0, stream, Hw,  200, 200, 0, HWh, HWl, 0);

  hipMemsetAsync(wbuf, 0, (size_t)B_*4, stream);

  hipLaunchKernelGGL(gather_x0, dim3(B_/256, TL_, NSEG_), dim3(256), 0, stream, text, emb, X0);

  // ---- conv stack ----
  for (int z = 0; z < NSEG_; ++z) {
    hipLaunchKernelGGL((pack_act<false,2>), dim3(48,10), dim3(256), 0, stream,
        X0 + (size_t)z*E_*TL_*B_, nullptr, nullptr, PKh, PKl, 300, TL_, 12288);
    hipLaunchKernelGGL((conv_gemm<false>), dim3(192), dim3(256), 0, stream,
        W1h, W1l, PKh, PKl, c1b, Y1 + (size_t)z*F_*6*B_, 10, 12288, 6);
  }
  hipLaunchKernelGGL(bn_stats, dim3(F_, NSEG_), dim3(256), 0, stream, Y1, 6, gamma, beta, S1, Sh1);
  for (int z = 0; z < NSEG_; ++z) {
    hipLaunchKernelGGL((pack_act<true,2>), dim3(40,13), dim3(256), 0, stream,
        Y1 + (size_t)z*F_*6*B_, S1 + z*F_, Sh1 + z*F_, PKh, PKl, 400, 6, 10240);
    hipLaunchKernelGGL((conv_gemm<false>), dim3(160), dim3(256), 0, stream,
        W2h, W2l, PKh, PKl, c2b, Y2 + (size_t)z*F_*5*B_, 13, 10240, 5);
  }
  hipLaunchKernelGGL(bn_stats, dim3(F_, NSEG_), dim3(256), 0, stream, Y2, 5, gamma, beta, S2, Sh2);
  for (int z = 0; z < NSEG_; ++z) {
    hipLaunchKernelGGL((pack_act<true,3>), dim3(24,19), dim3(256), 0, stream,
        Y2 + (size_t)z*F_*5*B_, S2 + z*F_, Sh2 + z*F_, PKh, PKl, 600, 5, 6144);
    hipLaunchKernelGGL((conv_gemm<false>), dim3(96), dim3(256), 0, stream,
        W3h, W3l, PKh, PKl, c3b, Y3 + (size_t)z*F_*3*B_, 19, 6144, 3);
  }
  hipLaunchKernelGGL(bn_stats, dim3(F_, NSEG_), dim3(256), 0, stream, Y3, 3, gamma, beta, S3, Sh3);
  for (int z = 0; z < NSEG_; ++z) {
    hipLaunchKernelGGL((pack_act<true,3>), dim3(8,19), dim3(256), 0, stream,
        Y3 + (size_t)z*F_*3*B_, S3 + z*F_, Sh3 + z*F_, PKh, PKl, 600, 3, 2048);
    hipLaunchKernelGGL((conv_gemm<true>), dim3(32), dim3(256), 0, stream,
        W4h, W4l, PKh, PKl, c4b, VEC + (size_t)z*F_*B_, 19, 2048, 1);
  }

  // ---- M chain (MFMA; all-packed) ----
  hipLaunchKernelGGL(pack_x, dim3(B_/256, KQ_, NSEG_), dim3(256), 0, stream,
      VEC, (long long)F_*B_, VPh, VPl, FRZ);
  hipMemsetAsync(hAh, 0, (size_t)2*KQ_*B_*32*2, stream);   // hAh + hAl contiguous -> h0 = 0
  u16 *hch = hAh, *hcl = hAl, *hnh = hBh, *hnl = hBl;
  for (int i = 0; i < 3; ++i) {
    hipLaunchKernelGGL((mf_gemm<true,true,false,true>), dim3(4, 32, 1), dim3(256), 0, stream,
        MW1h, MW1l, 0, VPh + (size_t)i*FRZ, VPl + (size_t)i*FRZ, 0,
        MW2h, MW2l, hch, hcl, Mb, 0, nullptr, 0, hnh, hnl);
    u16* t1 = hch; hch = hnh; hnh = t1;
    u16* t2 = hcl; hcl = hnl; hnl = t2;
  }
  // final h frags in hch/hcl

  // ---- U / us / H (MFMA) ----
  hipLaunchKernelGGL((mf_gemm<false,false,true,false>), dim3(4, 32, 6), dim3(256), 0, stream,
      UWh, UWl, WQZ, hch, hcl, 0, nullptr, nullptr, nullptr, nullptr,
      Ub + F_, F_, Uh + (size_t)F_*B_, (long long)F_*B_, nullptr, nullptr);
  hipLaunchKernelGGL(us_build, dim3(7*F_*B_/256), dim3(256), 0, stream, Uh, US);
  hipLaunchKernelGGL(pack_x, dim3(B_/256, KQ_, 7), dim3(256), 0, stream,
      US, (long long)F_*B_, USh, USl, FRZ);
  hipLaunchKernelGGL((mf_gemm<false,false,true,false>), dim3(4, 32, 7), dim3(256), 0, stream,
      HWh, HWl, 0, USh, USl, FRZ, nullptr, nullptr, nullptr, nullptr,
      Hb, 0, HT, (long long)F_*B_, nullptr, nullptr);

  // ---- scan prep (P-tail and Q overlays now stable) ----
  hipLaunchKernelGGL(transpose_k, dim3(313,7,1), tb_, 0, stream, Xw, XwT, F_, V_);
  hipLaunchKernelGGL(pack_yw, dim3(KQ_, (V_+255)/256), dim3(256), 0, stream, Yw, YWhi, YWlo);
  hipMemsetAsync(A0h, 0, (size_t)2*KQ_*B_*32*2, stream);   // zero r0 frags

  // ---- scan ----
  u16 *cin_h = A0h, *cin_l = A0l, *cout_h = A1h, *cout_l = A1l;
  for (int t = 0; t < 7; ++t) {
    hipLaunchKernelGGL(r_step, dim3(4, 32), dim3(256), 0, stream,
        RWh, RWl, cin_h, cin_l, Rb, XwT, Xb, HT + (size_t)t*F_*B_, wbuf, rA, cout_h, cout_l);
    hipLaunchKernelGGL(y_mfma, dim3(NYB), dim3(256), 0, stream,
        cout_h, cout_l, YWhi, YWlo, Yb, pm4);
    const int* tgt_t = text + (size_t)(21 + t)*B_;
    hipLaunchKernelGGL(combine2, dim3(B_), dim3(64), 0, stream,
        pm4, rA, Yw, Yb, tgt_t, wbuf, loss_rows + (size_t)t*B_, corr_rows + (size_t)t*B_);
    u16* th = cin_h; cin_h = cout_h; cout_h = th;
    u16* tl = cin_l; cin_l = cout_l; cout_l = tl;
  }

  hipLaunchKernelGGL(finalize_k, dim3(1), dim3(256), 0, stream, loss_rows, corr_rows, (float*)d_out);
}

// Round 9
// 1362.014 us; speedup vs baseline: 1.3548x; 1.0043x over previous
//
#include <hip/hip_runtime.h>
#include <math.h>

#define V_    10000
#define VP_   10048        // padded vocab for guard-free Y-GEMM (157*64)
#define E_    150
#define F_    200
#define TL_   7
#define B_    2048
#define NSEG_ 3
#define EPS_  1e-5f
#define SLOPE_ 0.01f
#define NB64  (B_/64)
#define NVB   157          // ceil(10000/64) v-parts for MFMA Y-GEMM
#define NYB   2560         // 8 xcd * 20 vb-slots * 16 b-tiles
#define KQ_   7            // K chunks of 32 for F_=200 (padded 224)

typedef unsigned short u16;
typedef __attribute__((ext_vector_type(8))) short bf16x8;
typedef __attribute__((ext_vector_type(4))) float f32x4;

__device__ __forceinline__ float leaky_f(float x){ return x >= 0.f ? x : SLOPE_*x; }
__device__ __forceinline__ u16 bf16_rne(float x){
  unsigned u = __float_as_uint(x);
  unsigned r = (u + 0x7FFFu + ((u>>16)&1u)) >> 16;
  return (u16)r;
}
__device__ __forceinline__ float bf16_to_f(u16 h){ return __uint_as_float(((unsigned)h)<<16); }

// ---------------------------------------------------------------- transpose (used for XwT only)
__global__ void transpose_k(const float* __restrict__ in, float* __restrict__ out,
                            int R, int C)
{
  __shared__ float tile[32][33];
  const long long bofs = (long long)blockIdx.z * R * C;
  in += bofs; out += bofs;
  const int c0 = blockIdx.x*32, r0 = blockIdx.y*32;
  const int tx = threadIdx.x, ty = threadIdx.y;  // (32,8)
  for (int i = ty; i < 32; i += 8) {
    int r = r0 + i, c = c0 + tx;
    if (r < R && c < C) tile[i][tx] = in[(long long)r*C + c];
  }
  __syncthreads();
  for (int i = ty; i < 32; i += 8) {
    int c = c0 + i, r = r0 + tx;
    if (c < C && r < R) out[(long long)c*R + r] = tile[tx][i];
  }
}

// ---------------------------------------------------------------- embedding gather
__global__ void gather_x0(const int* __restrict__ text, const float* __restrict__ emb,
                          float* __restrict__ X0)
{
  const int b = blockIdx.x*256 + threadIdx.x;
  const int l = blockIdx.y, j = blockIdx.z;
  const int s = j*TL_ + l;
  const int row = text[(long long)s*B_ + b];
  const float* er = emb + (long long)row*E_;
  float* xp = X0 + ((long long)j*E_*TL_ + l)*B_ + b;
  for (int e = 0; e < E_; ++e) xp[(long long)e*TL_*B_] = er[e];
}

// ---------------------------------------------------------------- weight pack
__global__ void pack_w(const float* __restrict__ W, int Kstride, int Keff, long long wZi,
                       u16* __restrict__ Wh, u16* __restrict__ Wl, long long wZo)
{
  const int q = blockIdx.x;
  const int z = blockIdx.y;
  const int f = threadIdx.x;        // 256
  W  += (size_t)z*wZi;
  Wh += (size_t)z*wZo; Wl += (size_t)z*wZo;
  union { u16 u[32]; uint4 v[4]; } H, L;
  #pragma unroll
  for (int kk = 0; kk < 32; ++kk) {
    const int k = q*32 + kk;
    const float x = (k < Keff && f < F_) ? W[(size_t)f*Kstride + k] : 0.f;
    const u16 h = bf16_rne(x);
    H.u[kk] = h;
    L.u[kk] = bf16_rne(x - bf16_to_f(h));
  }
  uint4* dh = (uint4*)(Wh + ((size_t)q*256 + f)*32);
  uint4* dl = (uint4*)(Wl + ((size_t)q*256 + f)*32);
  #pragma unroll
  for (int i = 0; i < 4; ++i) { dh[i] = H.v[i]; dl[i] = L.v[i]; }
}

// ---------------------------------------------------------------- pack fp32 [z][F][B] -> frags [z][q][B][32]
__global__ void pack_x(const float* __restrict__ X, long long xZ,
                       u16* __restrict__ Oh, u16* __restrict__ Ol, long long oZ)
{
  const int q = blockIdx.y, z = blockIdx.z;
  const int b = blockIdx.x*256 + threadIdx.x;
  X  += (size_t)z*xZ;
  Oh += (size_t)z*oZ; Ol += (size_t)z*oZ;
  union { u16 u[32]; uint4 v[4]; } H, L;
  #pragma unroll
  for (int kk = 0; kk < 32; ++kk) {
    const int k = q*32 + kk;
    const float x = (k < F_) ? X[(size_t)k*B_ + b] : 0.f;
    const u16 h = bf16_rne(x);
    H.u[kk] = h;
    L.u[kk] = bf16_rne(x - bf16_to_f(h));
  }
  uint4* dh = (uint4*)(Oh + ((size_t)q*B_ + b)*32);
  uint4* dl = (uint4*)(Ol + ((size_t)q*B_ + b)*32);
  #pragma unroll
  for (int i = 0; i < 4; ++i) { dh[i] = H.v[i]; dl[i] = L.v[i]; }
}

// ---------------------------------------------------------------- generic MFMA GEMM
template<bool TWO, bool LEAKY, bool OUT_F32, bool OUT_PK>
__global__ __launch_bounds__(256) void mf_gemm(
    const u16* __restrict__ W1h, const u16* __restrict__ W1l, long long wZ,
    const u16* __restrict__ X1h, const u16* __restrict__ X1l, long long xZ,
    const u16* __restrict__ W2h, const u16* __restrict__ W2l,
    const u16* __restrict__ X2h, const u16* __restrict__ X2l,
    const float* __restrict__ bias, long long bZ,
    float* __restrict__ Cf, long long cZ,
    u16* __restrict__ Oh, u16* __restrict__ Ol)
{
  const int z = blockIdx.z;
  W1h += (size_t)z*wZ; W1l += (size_t)z*wZ;
  X1h += (size_t)z*xZ; X1l += (size_t)z*xZ;
  const float* bz = bias + (size_t)z*bZ;
  if (OUT_F32) Cf += (size_t)z*cZ;

  const int f0 = blockIdx.x*64;
  const int b0 = blockIdx.y*64;
  const int tid = threadIdx.x;
  const int w = tid >> 6, l = tid & 63;
  const int lr = l & 15, g = l >> 4;

  __shared__ float T[64][65];

  f32x4 acc[4] = {};
  for (int q = 0; q < KQ_; ++q) {
    {
      const size_t aoff = ((size_t)q*256 + (f0 + w*16 + lr))*32 + g*8;
      const bf16x8 ah = *(const bf16x8*)(W1h + aoff);
      const bf16x8 al = *(const bf16x8*)(W1l + aoff);
      #pragma unroll
      for (int nt = 0; nt < 4; ++nt) {
        const size_t boff = ((size_t)q*B_ + (b0 + nt*16 + lr))*32 + g*8;
        const bf16x8 bh = *(const bf16x8*)(X1h + boff);
        const bf16x8 bl = *(const bf16x8*)(X1l + boff);
        acc[nt] = __builtin_amdgcn_mfma_f32_16x16x32_bf16(ah, bh, acc[nt], 0, 0, 0);
        acc[nt] = __builtin_amdgcn_mfma_f32_16x16x32_bf16(ah, bl, acc[nt], 0, 0, 0);
        acc[nt] = __builtin_amdgcn_mfma_f32_16x16x32_bf16(al, bh, acc[nt], 0, 0, 0);
      }
    }
    if (TWO) {
      const size_t aoff = ((size_t)q*256 + (f0 + w*16 + lr))*32 + g*8;
      const bf16x8 ah = *(const bf16x8*)(W2h + aoff);
      const bf16x8 al = *(const bf16x8*)(W2l + aoff);
      #pragma unroll
      for (int nt = 0; nt < 4; ++nt) {
        const size_t boff = ((size_t)q*B_ + (b0 + nt*16 + lr))*32 + g*8;
        const bf16x8 bh = *(const bf16x8*)(X2h + boff);
        const bf16x8 bl = *(const bf16x8*)(X2l + boff);
        acc[nt] = __builtin_amdgcn_mfma_f32_16x16x32_bf16(ah, bh, acc[nt], 0, 0, 0);
        acc[nt] = __builtin_amdgcn_mfma_f32_16x16x32_bf16(ah, bl, acc[nt], 0, 0, 0);
        acc[nt] = __builtin_amdgcn_mfma_f32_16x16x32_bf16(al, bh, acc[nt], 0, 0, 0);
      }
    }
  }
  #pragma unroll
  for (int nt = 0; nt < 4; ++nt)
    #pragma unroll
    for (int j = 0; j < 4; ++j)
      T[w*16 + g*4 + j][nt*16 + lr] = acc[nt][j];
  __syncthreads();

  const int ty = tid >> 4, tx = tid & 15;
  #pragma unroll
  for (int i = 0; i < 4; ++i) {
    const int f = f0 + ty*4 + i;
    if (f < F_) {
      const float bb = bz[f];
      #pragma unroll
      for (int j = 0; j < 4; ++j) {
        float v = T[ty*4 + i][tx*4 + j] + bb;
        if (LEAKY) v = leaky_f(v);
        if (OUT_F32) Cf[(size_t)f*B_ + b0 + tx*4 + j] = v;
        T[ty*4 + i][tx*4 + j] = v;
      }
    } else {
      #pragma unroll
      for (int j = 0; j < 4; ++j) T[ty*4 + i][tx*4 + j] = 0.f;
    }
  }
  __syncthreads();

  if (OUT_PK) {
    const int bcol = tid & 63;
    const int kk0 = (tid >> 6)*8;
    #pragma unroll
    for (int qh = 0; qh < 2; ++qh) {
      const int q = (f0 >> 5) + qh;
      if (q >= KQ_) continue;
      union { u16 u[8]; uint4 v2[1]; } H, L;
      #pragma unroll
      for (int u = 0; u < 8; ++u) {
        const float x = T[qh*32 + kk0 + u][bcol];
        const u16 h = bf16_rne(x);
        H.u[u] = h;
        L.u[u] = bf16_rne(x - bf16_to_f(h));
      }
      const size_t off = ((size_t)q*B_ + b0 + bcol)*32 + kk0;
      *(uint4*)(Oh + off) = H.v2[0];
      *(uint4*)(Ol + off) = L.v2[0];
    }
  }
}

// ---------------------------------------------------------------- activation pack (BN+leaky fused), per z (conv)
template<bool BN, int KW>
__global__ void pack_act(const float* __restrict__ Y,
                         const float* __restrict__ bnS, const float* __restrict__ bnH,
                         u16* __restrict__ Ph, u16* __restrict__ Pl,
                         int K, int Lin, int Ncols)
{
  const int q = blockIdx.y;
  const int c = blockIdx.x*256 + threadIdx.x;
  const int t = c >> 11, b = c & 2047;
  union { u16 u[32]; uint4 v[4]; } H, L;
  #pragma unroll
  for (int kk = 0; kk < 32; ++kk) {
    const int k = q*32 + kk;
    float x = 0.f;
    if (k < K) {
      const int e = k / KW, kw = k - e*KW;
      x = Y[((size_t)e*Lin + (t + kw))*B_ + b];
      if (BN) { x = fmaf(x, bnS[e], bnH[e]); x = leaky_f(x); }
    }
    const u16 h = bf16_rne(x);
    H.u[kk] = h;
    L.u[kk] = bf16_rne(x - bf16_to_f(h));
  }
  uint4* dh = (uint4*)(Ph + ((size_t)q*Ncols + c)*32);
  uint4* dl = (uint4*)(Pl + ((size_t)q*Ncols + c)*32);
  #pragma unroll
  for (int i = 0; i < 4; ++i) { dh[i] = H.v[i]; dl[i] = L.v[i]; }
}

// ---------------------------------------------------------------- conv GEMM
template<bool OUT_LEAKY>
__global__ __launch_bounds__(256) void conv_gemm(
    const u16* __restrict__ Wh, const u16* __restrict__ Wl,
    const u16* __restrict__ Ph, const u16* __restrict__ Pl,
    const float* __restrict__ bias, float* __restrict__ C,
    int NQ, int Ncols, int Lout)
{
  const int c0 = blockIdx.x*64;
  const int w  = threadIdx.x >> 6;
  const int l  = threadIdx.x & 63;
  const int lr = l & 15, g = l >> 4;

  f32x4 acc[4][4] = {};

  for (int q = 0; q < NQ; ++q) {
    bf16x8 bh[4], bl[4];
    #pragma unroll
    for (int nt = 0; nt < 4; ++nt) {
      const size_t off = ((size_t)q*Ncols + (c0 + nt*16 + lr))*32 + g*8;
      bh[nt] = *(const bf16x8*)(Ph + off);
      bl[nt] = *(const bf16x8*)(Pl + off);
    }
    #pragma unroll
    for (int mt = 0; mt < 4; ++mt) {
      const size_t woff = ((size_t)q*256 + (w*64 + mt*16 + lr))*32 + g*8;
      const bf16x8 ah = *(const bf16x8*)(Wh + woff);
      const bf16x8 al = *(const bf16x8*)(Wl + woff);
      #pragma unroll
      for (int nt = 0; nt < 4; ++nt) {
        acc[mt][nt] = __builtin_amdgcn_mfma_f32_16x16x32_bf16(ah, bh[nt], acc[mt][nt], 0, 0, 0);
        acc[mt][nt] = __builtin_amdgcn_mfma_f32_16x16x32_bf16(ah, bl[nt], acc[mt][nt], 0, 0, 0);
        acc[mt][nt] = __builtin_amdgcn_mfma_f32_16x16x32_bf16(al, bh[nt], acc[mt][nt], 0, 0, 0);
      }
    }
  }

  #pragma unroll
  for (int mt = 0; mt < 4; ++mt)
    #pragma unroll
    for (int j = 0; j < 4; ++j) {
      const int f = w*64 + mt*16 + g*4 + j;
      if (f < F_) {
        const float bs = bias[f];
        #pragma unroll
        for (int nt = 0; nt < 4; ++nt) {
          const int col = c0 + nt*16 + lr;
          const int t = col >> 11, b = col & 2047;
          float v = acc[mt][nt][j] + bs;
          if (OUT_LEAKY) v = leaky_f(v);
          C[((size_t)f*Lout + t)*B_ + b] = v;
        }
      }
    }
}

// ---------------------------------------------------------------- BN stats
__global__ void bn_stats(const float* __restrict__ Y, int L,
                         const float* __restrict__ gamma, const float* __restrict__ beta,
                         float* __restrict__ scale, float* __restrict__ shift)
{
  const int f = blockIdx.x, j = blockIdx.y;
  const float* p = Y + ((long long)(j*F_ + f))*L*B_;
  const int N = L*B_;
  double s = 0.0, s2 = 0.0;
  for (int i = threadIdx.x; i < N; i += 256) { double x = p[i]; s += x; s2 += x*x; }
  __shared__ double sh1[256], sh2[256];
  sh1[threadIdx.x] = s; sh2[threadIdx.x] = s2;
  __syncthreads();
  for (int off = 128; off; off >>= 1) {
    if (threadIdx.x < off) { sh1[threadIdx.x] += sh1[threadIdx.x+off]; sh2[threadIdx.x] += sh2[threadIdx.x+off]; }
    __syncthreads();
  }
  if (threadIdx.x == 0) {
    const double mean = sh1[0]/N;
    const double var  = sh2[0]/N - mean*mean;
    const float rstd = rsqrtf((float)var + EPS_);
    const float sc = gamma[f]*rstd;
    scale[j*F_+f] = sc;
    shift[j*F_+f] = beta[f] - (float)mean*sc;
  }
}

// ---------------------------------------------------------------- u_steps build
__global__ void us_build(const float* __restrict__ Uh, float* __restrict__ US)
{
  const long long i = (long long)blockIdx.x*256 + threadIdx.x;
  const long long FB = (long long)F_*B_;
  const int t = (int)(i / FB);
  const long long rem = i % FB;
  const int src = (t == 0) ? 6 : t;
  const float v = Uh[(long long)src*FB + rem];
  US[i] = (t < 5) ? leaky_f(v) : v;
}

// ---------------------------------------------------------------- fused scan step (MFMA): r-GEMM + finish + repack
__global__ __launch_bounds__(256) void r_step(
    const u16* __restrict__ RWh, const u16* __restrict__ RWl,
    const u16* __restrict__ Ain_h, const u16* __restrict__ Ain_l,
    const float* __restrict__ Rb, const float* __restrict__ XwT,
    const float* __restrict__ Xb, const float* __restrict__ HTt,
    const int* __restrict__ wprev,
    float* __restrict__ rn, u16* __restrict__ Ahi, u16* __restrict__ Alo)
{
  const int f0 = blockIdx.x*64;
  const int b0 = blockIdx.y*64;
  const int tid = threadIdx.x;
  const int w = tid >> 6, l = tid & 63;
  const int lr = l & 15, g = l >> 4;

  __shared__ float T[64][65];

  f32x4 acc[4] = {};
  for (int q = 0; q < KQ_; ++q) {
    const size_t aoff = ((size_t)q*256 + (f0 + w*16 + lr))*32 + g*8;
    const bf16x8 ah = *(const bf16x8*)(RWh + aoff);
    const bf16x8 al = *(const bf16x8*)(RWl + aoff);
    #pragma unroll
    for (int nt = 0; nt < 4; ++nt) {
      const size_t boff = ((size_t)q*B_ + (b0 + nt*16 + lr))*32 + g*8;
      const bf16x8 bh = *(const bf16x8*)(Ain_h + boff);
      const bf16x8 bl = *(const bf16x8*)(Ain_l + boff);
      acc[nt] = __builtin_amdgcn_mfma_f32_16x16x32_bf16(ah, bh, acc[nt], 0, 0, 0);
      acc[nt] = __builtin_amdgcn_mfma_f32_16x16x32_bf16(ah, bl, acc[nt], 0, 0, 0);
      acc[nt] = __builtin_amdgcn_mfma_f32_16x16x32_bf16(al, bh, acc[nt], 0, 0, 0);
    }
  }
  #pragma unroll
  for (int nt = 0; nt < 4; ++nt)
    #pragma unroll
    for (int j = 0; j < 4; ++j)
      T[w*16 + g*4 + j][nt*16 + lr] = acc[nt][j];
  __syncthreads();

  const int ty = tid >> 4, tx = tid & 15;
  int wv[4];
  #pragma unroll
  for (int j = 0; j < 4; ++j) {
    int t_ = wprev[b0 + tx*4 + j];
    wv[j] = (t_ < 0) ? 0 : (t_ >= V_ ? V_-1 : t_);
  }

  #pragma unroll
  for (int i = 0; i < 4; ++i) {
    const int f = f0 + ty*4 + i;
    if (f < F_) {
      const float rb = Rb[f] + Xb[f];
      #pragma unroll
      for (int j = 0; j < 4; ++j) {
        const int b = b0 + tx*4 + j;
        float v = T[ty*4 + i][tx*4 + j] + rb + XwT[(size_t)wv[j]*F_ + f] + HTt[(size_t)f*B_ + b];
        v = leaky_f(v);
        rn[(size_t)f*B_ + b] = v;
        T[ty*4 + i][tx*4 + j] = v;
      }
    } else {
      #pragma unroll
      for (int j = 0; j < 4; ++j) T[ty*4 + i][tx*4 + j] = 0.f;
    }
  }
  __syncthreads();

  const int bcol = tid & 63;
  const int kk0 = (tid >> 6)*8;
  #pragma unroll
  for (int qh = 0; qh < 2; ++qh) {
    const int q = (f0 >> 5) + qh;
    if (q >= KQ_) continue;
    union { u16 u[8]; uint4 v2[1]; } H, L;
    #pragma unroll
    for (int u = 0; u < 8; ++u) {
      const float x = T[qh*32 + kk0 + u][bcol];
      const u16 h = bf16_rne(x);
      H.u[u] = h;
      L.u[u] = bf16_rne(x - bf16_to_f(h));
    }
    const size_t off = ((size_t)q*B_ + b0 + bcol)*32 + kk0;
    *(uint4*)(Ahi + off) = H.v2[0];
    *(uint4*)(Alo + off) = L.v2[0];
  }
}

// ---------------------------------------------------------------- pack Yw -> padded B-frag planes [q][VP_][32]
__global__ void pack_yw(const float* __restrict__ Yw, u16* __restrict__ Bhi, u16* __restrict__ Blo)
{
  const int q = blockIdx.x;
  const int v = blockIdx.y*256 + threadIdx.x;
  if (v >= VP_) return;
  union { u16 u[32]; uint4 w[4]; } H, L;
  #pragma unroll
  for (int kk = 0; kk < 32; ++kk) {
    const int f = q*32 + kk;
    const float x = (f < F_ && v < V_) ? Yw[(size_t)v*F_ + f] : 0.f;
    const u16 h = bf16_rne(x);
    H.u[kk] = h;
    L.u[kk] = bf16_rne(x - bf16_to_f(h));
  }
  uint4* dh = (uint4*)(Bhi + ((size_t)q*VP_ + v)*32);
  uint4* dl = (uint4*)(Blo + ((size_t)q*VP_ + v)*32);
  #pragma unroll
  for (int i = 0; i < 4; ++i) { dh[i] = H.w[i]; dl[i] = L.w[i]; }
}

// ---------------------------------------------------------------- pad Yb: YbP[v] = v<V ? Yb[v] : -inf
__global__ void pad_yb(const float* __restrict__ Yb, float* __restrict__ YbP)
{
  const int v = blockIdx.x*256 + threadIdx.x;
  if (v < VP_) YbP[v] = (v < V_) ? Yb[v] : -INFINITY;
}

// ---------------------------------------------------------------- MFMA Y-GEMM v3: pipelined frags, guard-free
struct YFrag { bf16x8 ah[2], al[2], bh[4], bl[4]; };

__device__ __forceinline__ void y_loadq(YFrag& f, int q,
    const u16* __restrict__ Ahi, const u16* __restrict__ Alo,
    const u16* __restrict__ Bhi, const u16* __restrict__ Blo,
    int b0, int v0, int w, int lr, int g)
{
  #pragma unroll
  for (int mt = 0; mt < 2; ++mt) {
    const size_t o = ((size_t)q*B_ + (b0 + w*32 + mt*16 + lr))*32 + g*8;
    f.ah[mt] = *(const bf16x8*)(Ahi + o);
    f.al[mt] = *(const bf16x8*)(Alo + o);
  }
  #pragma unroll
  for (int nt = 0; nt < 4; ++nt) {
    const size_t o = ((size_t)q*VP_ + (v0 + nt*16 + lr))*32 + g*8;
    f.bh[nt] = *(const bf16x8*)(Bhi + o);
    f.bl[nt] = *(const bf16x8*)(Blo + o);
  }
}

__device__ __forceinline__ void y_mfmaq(const YFrag& f, f32x4 acc[2][4])
{
  #pragma unroll
  for (int mt = 0; mt < 2; ++mt)
    #pragma unroll
    for (int nt = 0; nt < 4; ++nt) {
      acc[mt][nt] = __builtin_amdgcn_mfma_f32_16x16x32_bf16(f.ah[mt], f.bh[nt], acc[mt][nt], 0, 0, 0);
      acc[mt][nt] = __builtin_amdgcn_mfma_f32_16x16x32_bf16(f.ah[mt], f.bl[nt], acc[mt][nt], 0, 0, 0);
      acc[mt][nt] = __builtin_amdgcn_mfma_f32_16x16x32_bf16(f.al[mt], f.bh[nt], acc[mt][nt], 0, 0, 0);
    }
}

__global__ __launch_bounds__(256) void y_mfma(
    const u16* __restrict__ Ahi, const u16* __restrict__ Alo,
    const u16* __restrict__ Bhi, const u16* __restrict__ Blo,
    const float* __restrict__ YbP, float4* __restrict__ pm4)
{
  const int bid = blockIdx.x;
  const int xcd = bid & 7;
  const int i   = bid >> 3;
  const int by  = i & 15;
  const int vb  = xcd*20 + (i >> 4);     // 0..159
  if (vb >= NVB) return;
  const int v0 = vb*64;
  const int b0 = by*128;
  const int w  = threadIdx.x >> 6;
  const int l  = threadIdx.x & 63;
  const int lr = l & 15;
  const int g  = l >> 4;

  f32x4 acc[2][4] = {};

  YFrag fA, fB;
  y_loadq(fA, 0, Ahi, Alo, Bhi, Blo, b0, v0, w, lr, g);
  #pragma unroll
  for (int q = 0; q < KQ_; ++q) {
    YFrag& cur = (q & 1) ? fB : fA;
    YFrag& nxt = (q & 1) ? fA : fB;
    if (q + 1 < KQ_)
      y_loadq(nxt, q + 1, Ahi, Alo, Bhi, Blo, b0, v0, w, lr, g);
    y_mfmaq(cur, acc);
  }

  // ---- pass 1: per-row max + argmax (padded cols give y = -inf) ----
  float ybv[4];
  #pragma unroll
  for (int nt = 0; nt < 4; ++nt) ybv[nt] = YbP[v0 + nt*16 + lr];

  float m[2][4]; int ai[2][4];
  #pragma unroll
  for (int mt = 0; mt < 2; ++mt)
    #pragma unroll
    for (int j = 0; j < 4; ++j) { m[mt][j] = -INFINITY; ai[mt][j] = 0x7fffffff; }

  #pragma unroll
  for (int nt = 0; nt < 4; ++nt) {
    const int colv = v0 + nt*16 + lr;
    #pragma unroll
    for (int mt = 0; mt < 2; ++mt)
      #pragma unroll
      for (int j = 0; j < 4; ++j) {
        const float y = acc[mt][nt][j] + ybv[nt];
        if (y > m[mt][j]) { m[mt][j] = y; ai[mt][j] = colv; }   // ascending colv -> first occurrence
      }
  }
  #pragma unroll
  for (int off = 1; off <= 8; off <<= 1) {
    #pragma unroll
    for (int mt = 0; mt < 2; ++mt)
      #pragma unroll
      for (int j = 0; j < 4; ++j) {
        const float om = __shfl_xor(m[mt][j], off);
        const int   oai = __shfl_xor(ai[mt][j], off);
        if (om > m[mt][j] || (om == m[mt][j] && oai < ai[mt][j])) { m[mt][j] = om; ai[mt][j] = oai; }
      }
  }

  // ---- pass 2: sum exp(y - rowmax); padded cols exp(-inf) = 0 ----
  float s[2][4] = {};
  #pragma unroll
  for (int nt = 0; nt < 4; ++nt) {
    #pragma unroll
    for (int mt = 0; mt < 2; ++mt)
      #pragma unroll
      for (int j = 0; j < 4; ++j)
        s[mt][j] += __expf(acc[mt][nt][j] + ybv[nt] - m[mt][j]);
  }
  #pragma unroll
  for (int off = 1; off <= 8; off <<= 1) {
    #pragma unroll
    for (int mt = 0; mt < 2; ++mt)
      #pragma unroll
      for (int j = 0; j < 4; ++j)
        s[mt][j] += __shfl_xor(s[mt][j], off);
  }

  if (lr == 0) {
    #pragma unroll
    for (int mt = 0; mt < 2; ++mt)
      #pragma unroll
      for (int j = 0; j < 4; ++j) {
        const int row = b0 + w*32 + mt*16 + g*4 + j;
        pm4[(size_t)vb*B_ + row] = make_float4(m[mt][j], s[mt][j], __int_as_float(ai[mt][j]), 0.f);
      }
  }
}

// ---------------------------------------------------------------- combine partials + exact fp32 target logit
__global__ void combine2(const float4* __restrict__ pm4,
                         const float* __restrict__ r, const float* __restrict__ Yw,
                         const float* __restrict__ Yb, const int* __restrict__ tgt,
                         int* __restrict__ w, float* __restrict__ loss_row,
                         int* __restrict__ corr_row)
{
  const int b = blockIdx.x;
  const int lane = threadIdx.x;      // 64
  const int tb = tgt[b];

  float td = 0.f;
  #pragma unroll
  for (int it = 0; it < 4; ++it) {
    const int f = lane + it*64;
    if (f < F_) td = fmaf(r[(size_t)f*B_ + b], Yw[(size_t)tb*F_ + f], td);
  }

  float M = -INFINITY, S = 0.f; int ai = 0x7fffffff;
  for (int p = lane; p < NVB; p += 64) {
    const float4 q = pm4[(size_t)p*B_ + b];
    const float mm = q.x, s = q.y;
    const int idx = __float_as_int(q.z);
    if (mm > M) ai = idx;
    else if (mm == M && idx < ai) ai = idx;
    const float M2 = fmaxf(M, mm);
    const float t1 = (M == -INFINITY) ? 0.f : S*__expf(M - M2);
    S = t1 + s*__expf(mm - M2);
    M = M2;
  }
  #pragma unroll
  for (int off = 1; off <= 32; off <<= 1) {
    td += __shfl_xor(td, off);
    const float om = __shfl_xor(M, off);
    const float os = __shfl_xor(S, off);
    const int   oai = __shfl_xor(ai, off);
    if (om > M) ai = oai;
    else if (om == M && oai < ai) ai = oai;
    const float M2 = fmaxf(M, om);
    const float t1 = (M  == -INFINITY) ? 0.f : S *__expf(M  - M2);
    const float t2 = (om == -INFINITY) ? 0.f : os*__expf(om - M2);
    S = t1 + t2;
    M = M2;
  }
  if (lane == 0) {
    const float logZ = M + logf(S);
    loss_row[b] = logZ - (td + Yb[tb]);
    corr_row[b] = (ai == tb) ? 1 : 0;
    w[b] = ai;
  }
}

// ---------------------------------------------------------------- final deterministic reduce
__global__ void finalize_k(const float* __restrict__ lr, const int* __restrict__ cr,
                           float* __restrict__ out)
{
  __shared__ float sf[256]; __shared__ int si[256];
  float s = 0.f; int c = 0;
  for (int i = threadIdx.x; i < 7*B_; i += 256) { s += lr[i]; c += cr[i]; }
  sf[threadIdx.x] = s; si[threadIdx.x] = c;
  __syncthreads();
  for (int off = 128; off; off >>= 1) {
    if (threadIdx.x < off) { sf[threadIdx.x] += sf[threadIdx.x+off]; si[threadIdx.x] += si[threadIdx.x+off]; }
    __syncthreads();
  }
  if (threadIdx.x == 0) { out[0] = sf[0] / (float)B_; out[1] = (float)si[0]; }
}

// ================================================================ host
extern "C" void kernel_launch(void* const* d_in, const int* in_sizes, int n_in,
                              void* d_out, int out_size, void* d_ws, size_t ws_size,
                              hipStream_t stream)
{
  (void)in_sizes; (void)n_in; (void)out_size; (void)ws_size;
  const int*   text = (const int*)d_in[0];
  const float* emb  = (const float*)d_in[3];
  const float* gamma= (const float*)d_in[4];
  const float* beta = (const float*)d_in[5];
  const float* c1w = (const float*)d_in[6];  const float* c1b = (const float*)d_in[7];
  const float* c2w = (const float*)d_in[8];  const float* c2b = (const float*)d_in[9];
  const float* c3w = (const float*)d_in[10]; const float* c3b = (const float*)d_in[11];
  const float* c4w = (const float*)d_in[12]; const float* c4b = (const float*)d_in[13];
  const float* Mw = (const float*)d_in[14];  const float* Mb = (const float*)d_in[15];
  const float* Uw = (const float*)d_in[16];  const float* Ub = (const float*)d_in[17];
  const float* Rw = (const float*)d_in[18];  const float* Rb = (const float*)d_in[19];
  const float* Hw = (const float*)d_in[20];  const float* Hb = (const float*)d_in[21];
  const float* Xw = (const float*)d_in[22];  const float* Xb = (const float*)d_in[23];
  const float* Yw = (const float*)d_in[24];  const float* Yb = (const float*)d_in[25];

  float* ws = (float*)d_ws;
  size_t off = 0;
  auto alloc = [&](size_t n)->float* { float* p = ws + off; off += (n + 63) & ~(size_t)63; return p; };

  // packed weights: [NQ][256][32] u16 hi/lo
  u16* W1h = (u16*)alloc((size_t)10*256*32/2); u16* W1l = (u16*)alloc((size_t)10*256*32/2);
  u16* W2h = (u16*)alloc((size_t)13*256*32/2); u16* W2l = (u16*)alloc((size_t)13*256*32/2);
  u16* W3h = (u16*)alloc((size_t)19*256*32/2); u16* W3l = (u16*)alloc((size_t)19*256*32/2);
  u16* W4h = (u16*)alloc((size_t)19*256*32/2); u16* W4l = (u16*)alloc((size_t)19*256*32/2);
  u16* RWh = (u16*)alloc((size_t)7*256*32/2);  u16* RWl = (u16*)alloc((size_t)7*256*32/2);
  u16* MW1h= (u16*)alloc((size_t)7*256*32/2);  u16* MW1l= (u16*)alloc((size_t)7*256*32/2);
  u16* MW2h= (u16*)alloc((size_t)7*256*32/2);  u16* MW2l= (u16*)alloc((size_t)7*256*32/2);
  u16* UWh = (u16*)alloc((size_t)6*7*256*32/2);u16* UWl = (u16*)alloc((size_t)6*7*256*32/2);
  u16* HWh = (u16*)alloc((size_t)7*256*32/2);  u16* HWl = (u16*)alloc((size_t)7*256*32/2);
  float* S1 = alloc(3*F_); float* Sh1 = alloc(3*F_);
  float* S2 = alloc(3*F_); float* Sh2 = alloc(3*F_);
  float* S3 = alloc(3*F_); float* Sh3 = alloc(3*F_);
  float* YbP = alloc(VP_);
  float* P  = alloc((size_t)NSEG_*E_*TL_*B_);     // X0 -> Y2 -> HT + packed planes
  float* Q  = alloc((size_t)NSEG_*F_*6*B_);       // Y1 -> Y3 -> Uh+US+hpk -> pm4+XwT
  float* VEC = alloc((size_t)NSEG_*F_*B_);
  float* rA = alloc((size_t)F_*B_);
  u16* PKh = (u16*)alloc((size_t)13*10240*32/2);
  u16* PKl = (u16*)alloc((size_t)13*10240*32/2);
  int*   wbuf = (int*)alloc(B_);
  float* loss_rows = alloc((size_t)7*B_);
  int*   corr_rows = (int*)alloc((size_t)7*B_);

  float* X0 = P;                                   // [3][150][7][B]
  float* Y1 = Q;                                   // [3][200][6][B]
  float* Y2 = P;                                   // [3][200][5][B]
  float* Y3 = Q;                                   // [3][200][3][B]
  float* Uh = Q;                                   // [7][200][B]
  float* US = Q + (size_t)7*F_*B_;                 // [7][200][B]
  float* HT = P;                                   // [7][200][B] live through scan

  const size_t HT_FL = (size_t)7*F_*B_;            // 2,867,200 floats
  u16* YWhi = (u16*)(P + HT_FL);
  u16* YWlo = YWhi + (size_t)KQ_*VP_*32;           // 2,250,752 u16 each (padded)
  u16* A0h  = YWlo + (size_t)KQ_*VP_*32;
  u16* A0l  = A0h + (size_t)KQ_*B_*32;             // 458,752 u16 each
  u16* A1h  = A0l + (size_t)KQ_*B_*32;
  u16* A1l  = A1h + (size_t)KQ_*B_*32;
  // tail ends at P + 6,035,456 fl <= 6,451,200 OK

  // h fragment double-buffer in Q tail (after US region: 5,734,400)
  u16* hAh = (u16*)(Q + (size_t)5734400);
  u16* hAl = hAh + (size_t)KQ_*B_*32;
  u16* hBh = hAl + (size_t)KQ_*B_*32;
  u16* hBl = hBh + (size_t)KQ_*B_*32;              // ends Q + 6,651,904 fl <= 7,372,800 OK

  u16* VPh = PKh;  u16* VPl = PKl;                 // vec frags overlay conv pack buffer
  u16* USh = PKh;  u16* USl = PKl;                 // us frags overlay conv pack buffer

  float4* pm4 = (float4*)Q;                        // scan: [NVB][B_] float4
  float*  XwT = Q + (size_t)2097152;               // scan: [V][F]

  const long long FRZ = (long long)KQ_*B_*32;      // frag z-stride (u16 elems)
  const long long WQZ = (long long)KQ_*256*32;     // packed-weight z-stride

  const dim3 tb_(32,8);
  // weight packs
  hipLaunchKernelGGL(pack_w, dim3(10,1), dim3(256), 0, stream, c1w, 300, 300, 0, W1h, W1l, 0);
  hipLaunchKernelGGL(pack_w, dim3(13,1), dim3(256), 0, stream, c2w, 400, 400, 0, W2h, W2l, 0);
  hipLaunchKernelGGL(pack_w, dim3(19,1), dim3(256), 0, stream, c3w, 600, 600, 0, W3h, W3l, 0);
  hipLaunchKernelGGL(pack_w, dim3(19,1), dim3(256), 0, stream, c4w, 600, 600, 0, W4h, W4l, 0);
  hipLaunchKernelGGL(pack_w, dim3(7,1),  dim3(256), 0, stream, Rw,  200, 200, 0, RWh, RWl, 0);
  hipLaunchKernelGGL(pack_w, dim3(7,1),  dim3(256), 0, stream, Mw,       400, 200, 0, MW1h, MW1l, 0);
  hipLaunchKernelGGL(pack_w, dim3(7,1),  dim3(256), 0, stream, Mw + 200, 400, 200, 0, MW2h, MW2l, 0);
  hipLaunchKernelGGL(pack_w, dim3(7,6),  dim3(256), 0, stream, Uw + (size_t)F_*F_, 200, 200, (long long)F_*F_, UWh, UWl, WQZ);
  hipLaunchKernelGGL(pack_w, dim3(7,1),  dim3(256), 0, stream, Hw,  200, 200, 0, HWh, HWl, 0);

  hipMemsetAsync(wbuf, 0, (size_t)B_*4, stream);

  hipLaunchKernelGGL(gather_x0, dim3(B_/256, TL_, NSEG_), dim3(256), 0, stream, text, emb, X0);

  // ---- conv stack ----
  for (int z = 0; z < NSEG_; ++z) {
    hipLaunchKernelGGL((pack_act<false,2>), dim3(48,10), dim3(256), 0, stream,
        X0 + (size_t)z*E_*TL_*B_, nullptr, nullptr, PKh, PKl, 300, TL_, 12288);
    hipLaunchKernelGGL((conv_gemm<false>), dim3(192), dim3(256), 0, stream,
        W1h, W1l, PKh, PKl, c1b, Y1 + (size_t)z*F_*6*B_, 10, 12288, 6);
  }
  hipLaunchKernelGGL(bn_stats, dim3(F_, NSEG_), dim3(256), 0, stream, Y1, 6, gamma, beta, S1, Sh1);
  for (int z = 0; z < NSEG_; ++z) {
    hipLaunchKernelGGL((pack_act<true,2>), dim3(40,13), dim3(256), 0, stream,
        Y1 + (size_t)z*F_*6*B_, S1 + z*F_, Sh1 + z*F_, PKh, PKl, 400, 6, 10240);
    hipLaunchKernelGGL((conv_gemm<false>), dim3(160), dim3(256), 0, stream,
        W2h, W2l, PKh, PKl, c2b, Y2 + (size_t)z*F_*5*B_, 13, 10240, 5);
  }
  hipLaunchKernelGGL(bn_stats, dim3(F_, NSEG_), dim3(256), 0, stream, Y2, 5, gamma, beta, S2, Sh2);
  for (int z = 0; z < NSEG_; ++z) {
    hipLaunchKernelGGL((pack_act<true,3>), dim3(24,19), dim3(256), 0, stream,
        Y2 + (size_t)z*F_*5*B_, S2 + z*F_, Sh2 + z*F_, PKh, PKl, 600, 5, 6144);
    hipLaunchKernelGGL((conv_gemm<false>), dim3(96), dim3(256), 0, stream,
        W3h, W3l, PKh, PKl, c3b, Y3 + (size_t)z*F_*3*B_, 19, 6144, 3);
  }
  hipLaunchKernelGGL(bn_stats, dim3(F_, NSEG_), dim3(256), 0, stream, Y3, 3, gamma, beta, S3, Sh3);
  for (int z = 0; z < NSEG_; ++z) {
    hipLaunchKernelGGL((pack_act<true,3>), dim3(8,19), dim3(256), 0, stream,
        Y3 + (size_t)z*F_*3*B_, S3 + z*F_, Sh3 + z*F_, PKh, PKl, 600, 3, 2048);
    hipLaunchKernelGGL((conv_gemm<true>), dim3(32), dim3(256), 0, stream,
        W4h, W4l, PKh, PKl, c4b, VEC + (size_t)z*F_*B_, 19, 2048, 1);
  }

  // ---- M chain (MFMA; all-packed) ----
  hipLaunchKernelGGL(pack_x, dim3(B_/256, KQ_, NSEG_), dim3(256), 0, stream,
      VEC, (long long)F_*B_, VPh, VPl, FRZ);
  hipMemsetAsync(hAh, 0, (size_t)2*KQ_*B_*32*2, stream);   // hAh + hAl contiguous -> h0 = 0
  u16 *hch = hAh, *hcl = hAl, *hnh = hBh, *hnl = hBl;
  for (int i = 0; i < 3; ++i) {
    hipLaunchKernelGGL((mf_gemm<true,true,false,true>), dim3(4, 32, 1), dim3(256), 0, stream,
        MW1h, MW1l, 0, VPh + (size_t)i*FRZ, VPl + (size_t)i*FRZ, 0,
        MW2h, MW2l, hch, hcl, Mb, 0, nullptr, 0, hnh, hnl);
    u16* t1 = hch; hch = hnh; hnh = t1;
    u16* t2 = hcl; hcl = hnl; hnl = t2;
  }

  // ---- U / us / H (MFMA) ----
  hipLaunchKernelGGL((mf_gemm<false,false,true,false>), dim3(4, 32, 6), dim3(256), 0, stream,
      UWh, UWl, WQZ, hch, hcl, 0, nullptr, nullptr, nullptr, nullptr,
      Ub + F_, F_, Uh + (size_t)F_*B_, (long long)F_*B_, nullptr, nullptr);
  hipLaunchKernelGGL(us_build, dim3(7*F_*B_/256), dim3(256), 0, stream, Uh, US);
  hipLaunchKernelGGL(pack_x, dim3(B_/256, KQ_, 7), dim3(256), 0, stream,
      US, (long long)F_*B_, USh, USl, FRZ);
  hipLaunchKernelGGL((mf_gemm<false,false,true,false>), dim3(4, 32, 7), dim3(256), 0, stream,
      HWh, HWl, 0, USh, USl, FRZ, nullptr, nullptr, nullptr, nullptr,
      Hb, 0, HT, (long long)F_*B_, nullptr, nullptr);

  // ---- scan prep (P-tail and Q overlays now stable) ----
  hipLaunchKernelGGL(transpose_k, dim3(313,7,1), tb_, 0, stream, Xw, XwT, F_, V_);
  hipLaunchKernelGGL(pack_yw, dim3(KQ_, (VP_+255)/256), dim3(256), 0, stream, Yw, YWhi, YWlo);
  hipLaunchKernelGGL(pad_yb, dim3((VP_+255)/256), dim3(256), 0, stream, Yb, YbP);
  hipMemsetAsync(A0h, 0, (size_t)2*KQ_*B_*32*2, stream);   // zero r0 frags

  // ---- scan ----
  u16 *cin_h = A0h, *cin_l = A0l, *cout_h = A1h, *cout_l = A1l;
  for (int t = 0; t < 7; ++t) {
    hipLaunchKernelGGL(r_step, dim3(4, 32), dim3(256), 0, stream,
        RWh, RWl, cin_h, cin_l, Rb, XwT, Xb, HT + (size_t)t*F_*B_, wbuf, rA, cout_h, cout_l);
    hipLaunchKernelGGL(y_mfma, dim3(NYB), dim3(256), 0, stream,
        cout_h, cout_l, YWhi, YWlo, YbP, pm4);
    const int* tgt_t = text + (size_t)(21 + t)*B_;
    hipLaunchKernelGGL(combine2, dim3(B_), dim3(64), 0, stream,
        pm4, rA, Yw, Yb, tgt_t, wbuf, loss_rows + (size_t)t*B_, corr_rows + (size_t)t*B_);
    u16* th = cin_h; cin_h = cout_h; cout_h = th;
    u16* tl = cin_l; cin_l = cout_l; cout_l = tl;
  }

  hipLaunchKernelGGL(finalize_k, dim3(1), dim3(256), 0, stream, loss_rows, corr_rows, (float*)d_out);
}